// Round 1
// baseline (1587.895 us; speedup 1.0000x reference)
//
#include <hip/hip_runtime.h>
#include <cstddef>
#include <cstdint>

#define N_NODES 50000
#define D_NODES 20000
#define M_NODES 30000
#define E_EDGES 800000
#define PAIRS_N 100000

// ---------------- utility kernels ----------------
__global__ void zero_int_kernel(int* p, int n) {
  int i = blockIdx.x * 256 + threadIdx.x;
  if (i < n) p[i] = 0;
}

__global__ void deg_count_kernel(const int* __restrict__ dst, int* __restrict__ degs, int e) {
  int i = blockIdx.x * 256 + threadIdx.x;
  if (i < e) atomicAdd(&degs[dst[i]], 1);
}

__global__ void norm_kernel(const int* __restrict__ degs, float* __restrict__ norm, int n) {
  int i = blockIdx.x * 256 + threadIdx.x;
  if (i < n) norm[i] = rsqrtf(fmaxf((float)degs[i], 1.0f));
}

__global__ void reduce256_kernel(const int* __restrict__ v, int n, int* __restrict__ bsums) {
  __shared__ int s[256];
  int t = threadIdx.x;
  int i = blockIdx.x * 256 + t;
  s[t] = (i < n) ? v[i] : 0;
  __syncthreads();
  for (int st = 128; st > 0; st >>= 1) {
    if (t < st) s[t] += s[t + st];
    __syncthreads();
  }
  if (t == 0) bsums[blockIdx.x] = s[0];
}

__global__ void scan_small_kernel(int* b, int nb) {
  __shared__ int s[256];
  int t = threadIdx.x;
  int orig = (t < nb) ? b[t] : 0;
  s[t] = orig;
  __syncthreads();
  for (int st = 1; st < 256; st <<= 1) {
    int v = (t >= st) ? s[t - st] : 0;
    __syncthreads();
    s[t] += v;
    __syncthreads();
  }
  if (t < nb) b[t] = s[t] - orig;  // exclusive
}

__global__ void scan_final_kernel(const int* __restrict__ degs, const int* __restrict__ boff,
                                  int* __restrict__ out, int n, int total) {
  __shared__ int s[256];
  int t = threadIdx.x;
  int i = blockIdx.x * 256 + t;
  int orig = (i < n) ? degs[i] : 0;
  s[t] = orig;
  __syncthreads();
  for (int st = 1; st < 256; st <<= 1) {
    int v = (t >= st) ? s[t - st] : 0;
    __syncthreads();
    s[t] += v;
    __syncthreads();
  }
  if (i < n) out[i] = boff[blockIdx.x] + s[t] - orig;  // global exclusive
  if (i == 0) out[n] = total;
}

__global__ void copy_int_kernel(const int* __restrict__ a, int* __restrict__ b, int n) {
  int i = blockIdx.x * 256 + threadIdx.x;
  if (i < n) b[i] = a[i];
}

__global__ void fill_csr_kernel(const int* __restrict__ esrc, const int* __restrict__ edst,
                                int* __restrict__ cursor, int* __restrict__ csr_src, int e) {
  int i = blockIdx.x * 256 + threadIdx.x;
  if (i < e) {
    int p = atomicAdd(&cursor[edst[i]], 1);
    csr_src[p] = esrc[i];
  }
}

// out[d,:] = norm[d] * sum_{e: dst=d} in[src[e],:] * norm[src[e]]
__global__ void prop_kernel(const float* __restrict__ in, int ldin,
                            float* __restrict__ out, int ldout,
                            const int* __restrict__ off, const int* __restrict__ srcs,
                            const float* __restrict__ norm, int width) {
  int node = blockIdx.x;
  int e0 = off[node], e1 = off[node + 1];
  float nd = norm[node];
  for (int c = threadIdx.x; c < width; c += blockDim.x) {
    float acc = 0.f;
    for (int e = e0; e < e1; ++e) {
      int s = srcs[e];
      acc += in[(size_t)s * ldin + c] * norm[s];
    }
    out[(size_t)node * ldout + c] = acc * nd;
  }
}

// ---------------- fp32 GEMM: C[r, colOff+0..127] = [A1|A2](row) @ W^T (+bias, act)
// W is [128, K] row-major. Tile: 64 rows x 128 cols per block, 256 threads, 8x4 per thread.
// Optional row gather (gsrc/gdst for the pair predictor: k<K1 -> row gsrc[r], else gdst[r]).
// act: 0 none, 1 ELU, 2 ReLU
__global__ __launch_bounds__(256) void gemm128_kernel(
    const float* __restrict__ A1, int lda1, int K1,
    const float* __restrict__ A2, int lda2, int K2,
    const int* __restrict__ gsrc, const int* __restrict__ gdst,
    const float* __restrict__ W, const float* __restrict__ bias,
    float* __restrict__ C, int ldc, int colOff,
    int row0, int nrows, int act) {
  __shared__ float As[32][68];    // [k][row], padded
  __shared__ float Ws[32][132];   // [k][col], padded
  const int tid = threadIdx.x;
  const int tx = tid & 31;        // col group: cols tx*4..tx*4+3
  const int ty = tid >> 5;        // row group: rows ty*8..ty*8+7
  const int brow = blockIdx.x * 64;
  const int K = K1 + K2;

  float acc[8][4];
#pragma unroll
  for (int i = 0; i < 8; ++i)
#pragma unroll
    for (int j = 0; j < 4; ++j) acc[i][j] = 0.f;

  const int sr = tid >> 2, skg = tid & 3;   // A staging: row sr, k-block skg*8
  const int wc = tid >> 1, wkg = tid & 1;   // W staging: col wc, k-block wkg*16

  for (int kc = 0; kc < K; kc += 32) {
    // ---- load A chunk to regs
    float4 v0 = make_float4(0, 0, 0, 0), v1 = make_float4(0, 0, 0, 0);
    {
      int grow = brow + sr;
      if (grow < nrows) {
        const float* base;
        int kk;
        if (gsrc) {
          int node = (kc < K1) ? gsrc[grow] : gdst[grow];
          base = A1 + (size_t)node * lda1;
          kk = (kc < K1) ? kc : (kc - K1);
        } else if (kc < K1) {
          base = A1 + (size_t)(row0 + grow) * lda1;
          kk = kc;
        } else {
          base = A2 + (size_t)(row0 + grow) * lda2;
          kk = kc - K1;
        }
        const float* p = base + kk + skg * 8;
        v0 = *(const float4*)p;
        v1 = *(const float4*)(p + 4);
      }
    }
    // ---- load W chunk to regs
    const float* wp = W + (size_t)wc * K + kc + wkg * 16;
    float4 u0 = *(const float4*)wp;
    float4 u1 = *(const float4*)(wp + 4);
    float4 u2 = *(const float4*)(wp + 8);
    float4 u3 = *(const float4*)(wp + 12);

    __syncthreads();  // previous iter's consumers done
    {
      int k0 = skg * 8;
      As[k0 + 0][sr] = v0.x; As[k0 + 1][sr] = v0.y; As[k0 + 2][sr] = v0.z; As[k0 + 3][sr] = v0.w;
      As[k0 + 4][sr] = v1.x; As[k0 + 5][sr] = v1.y; As[k0 + 6][sr] = v1.z; As[k0 + 7][sr] = v1.w;
      int kw = wkg * 16;
      Ws[kw + 0][wc] = u0.x;  Ws[kw + 1][wc] = u0.y;  Ws[kw + 2][wc] = u0.z;  Ws[kw + 3][wc] = u0.w;
      Ws[kw + 4][wc] = u1.x;  Ws[kw + 5][wc] = u1.y;  Ws[kw + 6][wc] = u1.z;  Ws[kw + 7][wc] = u1.w;
      Ws[kw + 8][wc] = u2.x;  Ws[kw + 9][wc] = u2.y;  Ws[kw + 10][wc] = u2.z; Ws[kw + 11][wc] = u2.w;
      Ws[kw + 12][wc] = u3.x; Ws[kw + 13][wc] = u3.y; Ws[kw + 14][wc] = u3.z; Ws[kw + 15][wc] = u3.w;
    }
    __syncthreads();

#pragma unroll 8
    for (int k = 0; k < 32; ++k) {
      float4 a0 = *(const float4*)&As[k][ty * 8];
      float4 a1 = *(const float4*)&As[k][ty * 8 + 4];
      float4 wv = *(const float4*)&Ws[k][tx * 4];
      float a[8] = {a0.x, a0.y, a0.z, a0.w, a1.x, a1.y, a1.z, a1.w};
      float wr[4] = {wv.x, wv.y, wv.z, wv.w};
#pragma unroll
      for (int i = 0; i < 8; ++i)
#pragma unroll
        for (int j = 0; j < 4; ++j) acc[i][j] += a[i] * wr[j];
    }
  }

  // ---- epilogue
#pragma unroll
  for (int i = 0; i < 8; ++i) {
    int grow = brow + ty * 8 + i;
    if (grow >= nrows) continue;
    float o[4];
#pragma unroll
    for (int j = 0; j < 4; ++j) {
      float v = acc[i][j];
      if (bias) v += bias[tx * 4 + j];
      if (act == 1) v = (v > 0.f) ? v : (expf(v) - 1.f);       // ELU
      else if (act == 2) v = fmaxf(v, 0.f);                     // ReLU
      o[j] = v;
    }
    float4 o4 = make_float4(o[0], o[1], o[2], o[3]);
    *(float4*)&C[(size_t)(row0 + grow) * ldc + colOff + tx * 4] = o4;
  }
}

// score[p] = sigmoid(dot(hidden[p], p1w) + p1b)
__global__ void score_kernel(const float* __restrict__ hidden, const float* __restrict__ p1w,
                             const float* __restrict__ p1b, float* __restrict__ out, int pairs) {
  int pr = blockIdx.x * 4 + (threadIdx.x >> 6);
  int lane = threadIdx.x & 63;
  if (pr >= pairs) return;
  const float* h = hidden + (size_t)pr * 128;
  float v = h[lane] * p1w[lane] + h[lane + 64] * p1w[lane + 64];
  for (int off = 32; off > 0; off >>= 1) v += __shfl_down(v, off);
  if (lane == 0) out[pr] = 1.f / (1.f + expf(-(v + p1b[0])));
}

// ---------------- host launcher ----------------
extern "C" void kernel_launch(void* const* d_in, const int* in_sizes, int n_in,
                              void* d_out, int out_size, void* d_ws, size_t ws_size,
                              hipStream_t stream) {
  const float* d_sim   = (const float*)d_in[0];
  const float* m_sim   = (const float*)d_in[1];
  const int*   e_src   = (const int*)d_in[2];
  const int*   e_dst   = (const int*)d_in[3];
  const int*   p_src   = (const int*)d_in[4];
  const int*   p_dst   = (const int*)d_in[5];
  const float* d_fc_w  = (const float*)d_in[6];
  const float* d_fc_b  = (const float*)d_in[7];
  const float* m_fc_w  = (const float*)d_in[8];
  const float* m_fc_b  = (const float*)d_in[9];
  const float* l0_w    = (const float*)d_in[10];
  const float* l1_w    = (const float*)d_in[11];
  const float* fc_w    = (const float*)d_in[12];
  const float* d_fc1_w = (const float*)d_in[13];
  const float* d_fc1_b = (const float*)d_in[14];
  const float* m_fc1_w = (const float*)d_in[15];
  const float* m_fc1_b = (const float*)d_in[16];
  const float* p0_w    = (const float*)d_in[17];
  const float* p0_b    = (const float*)d_in[18];
  const float* p1_w    = (const float*)d_in[19];
  const float* p1_b    = (const float*)d_in[20];
  float* out = (float*)d_out;

  const int N = N_NODES, D = D_NODES, M = M_NODES, E = E_EDGES, NP = PAIRS_N;

  // workspace layout (floats)
  const size_t B = (size_t)N * 384;
  float* ws = (float*)d_ws;
  float* buf0 = ws;
  float* buf1 = ws + B;
  float* buf2 = ws + 2 * B;
  float* normp = ws + 3 * B;
  int* degs    = (int*)(normp + N);
  int* csr_off = degs + N;          // N+1
  int* cursor  = csr_off + N + 1;
  int* csr_src = cursor + N;        // E
  int* bsums   = csr_src + E;       // <=256

  const int nb = (N + 255) / 256;   // 196
  const int eb = (E + 255) / 256;

  // ---- degrees, norm, CSR-by-dst
  zero_int_kernel<<<nb, 256, 0, stream>>>(degs, N);
  deg_count_kernel<<<eb, 256, 0, stream>>>(e_dst, degs, E);
  norm_kernel<<<nb, 256, 0, stream>>>(degs, normp, N);
  reduce256_kernel<<<nb, 256, 0, stream>>>(degs, N, bsums);
  scan_small_kernel<<<1, 256, 0, stream>>>(bsums, nb);
  scan_final_kernel<<<nb, 256, 0, stream>>>(degs, bsums, csr_off, N, E);
  copy_int_kernel<<<nb, 256, 0, stream>>>(csr_off, cursor, N);
  fill_csr_kernel<<<eb, 256, 0, stream>>>(e_src, e_dst, cursor, csr_src, E);

  const int GD = (D + 63) / 64;     // 313
  const int GM = (M + 63) / 64;     // 469
  const int GN = (N + 63) / 64;     // 782
  const int GP = (NP + 63) / 64;    // 1563

  // ---- input projections -> buf0 [N,128]
  gemm128_kernel<<<GD, 256, 0, stream>>>(d_sim, 512, 512, nullptr, 0, 0, nullptr, nullptr,
                                         d_fc_w, d_fc_b, buf0, 128, 0, 0, D, 0);
  gemm128_kernel<<<GM, 256, 0, stream>>>(m_sim, 512, 512, nullptr, 0, 0, nullptr, nullptr,
                                         m_fc_w, m_fc_b, buf0, 128, 0, D, M, 0);

  // ---- MixHop layer 0: in buf0 [N,128] -> out buf1 [N,384]
  gemm128_kernel<<<GN, 256, 0, stream>>>(buf0, 128, 128, nullptr, 0, 0, nullptr, nullptr,
                                         l0_w + 0 * 128 * 128, nullptr, buf1, 384, 0, 0, N, 0);
  prop_kernel<<<N, 128, 0, stream>>>(buf0, 128, buf2, 128, csr_off, csr_src, normp, 128);
  gemm128_kernel<<<GN, 256, 0, stream>>>(buf2, 128, 128, nullptr, 0, 0, nullptr, nullptr,
                                         l0_w + 1 * 128 * 128, nullptr, buf1, 384, 128, 0, N, 0);
  prop_kernel<<<N, 128, 0, stream>>>(buf2, 128, buf0, 128, csr_off, csr_src, normp, 128);
  gemm128_kernel<<<GN, 256, 0, stream>>>(buf0, 128, 128, nullptr, 0, 0, nullptr, nullptr,
                                         l0_w + 2 * 128 * 128, nullptr, buf1, 384, 256, 0, N, 0);

  // ---- MixHop layer 1: in buf1 [N,384] -> out buf2 [N,384]
  gemm128_kernel<<<GN, 256, 0, stream>>>(buf1, 384, 384, nullptr, 0, 0, nullptr, nullptr,
                                         l1_w + 0 * 128 * 384, nullptr, buf2, 384, 0, 0, N, 0);
  prop_kernel<<<N, 128, 0, stream>>>(buf1, 384, buf0, 384, csr_off, csr_src, normp, 384);
  gemm128_kernel<<<GN, 256, 0, stream>>>(buf0, 384, 384, nullptr, 0, 0, nullptr, nullptr,
                                         l1_w + 1 * 128 * 384, nullptr, buf2, 384, 128, 0, N, 0);
  prop_kernel<<<N, 128, 0, stream>>>(buf0, 384, buf1, 384, csr_off, csr_src, normp, 384);
  gemm128_kernel<<<GN, 256, 0, stream>>>(buf1, 384, 384, nullptr, 0, 0, nullptr, nullptr,
                                         l1_w + 2 * 128 * 384, nullptr, buf2, 384, 256, 0, N, 0);

  // ---- fc: buf2 [N,384] -> buf0 [N,128]
  gemm128_kernel<<<GN, 256, 0, stream>>>(buf2, 384, 384, nullptr, 0, 0, nullptr, nullptr,
                                         fc_w, nullptr, buf0, 128, 0, 0, N, 0);

  // ---- fc1 (concat with sims) + ELU -> h in buf1 [N,128]
  gemm128_kernel<<<GD, 256, 0, stream>>>(buf0, 128, 128, d_sim, 512, 512, nullptr, nullptr,
                                         d_fc1_w, d_fc1_b, buf1, 128, 0, 0, D, 1);
  gemm128_kernel<<<GM, 256, 0, stream>>>(buf0, 128, 128, m_sim, 512, 512, nullptr, nullptr,
                                         m_fc1_w, m_fc1_b, buf1, 128, 0, D, M, 1);

  // ---- predictor p0 (gathered concat rows) + ReLU -> hidden in buf2 [NP,128]
  gemm128_kernel<<<GP, 256, 0, stream>>>(buf1, 128, 128, buf1, 128, 128, p_src, p_dst,
                                         p0_w, p0_b, buf2, 128, 0, 0, NP, 2);

  // ---- final dot + sigmoid
  score_kernel<<<(NP + 3) / 4, 256, 0, stream>>>(buf2, p1_w, p1_b, out, NP);

  (void)in_sizes; (void)n_in; (void)out_size; (void)ws_size;
}

// Round 2
// 680.314 us; speedup vs baseline: 2.3341x; 2.3341x over previous
//
#include <hip/hip_runtime.h>
#include <cstddef>
#include <cstdint>

#define N_NODES 50000
#define D_NODES 20000
#define M_NODES 30000
#define E_EDGES 800000
#define PAIRS_N 100000

typedef unsigned short u16;
typedef unsigned int u32;
typedef short bf16x8 __attribute__((ext_vector_type(8)));
typedef float f32x4 __attribute__((ext_vector_type(4)));

__device__ __forceinline__ float bf2f(u16 u) {
  u32 v = ((u32)u) << 16;
  return __builtin_bit_cast(float, v);
}
__device__ __forceinline__ u16 f2bf(float f) {
  u32 u = __builtin_bit_cast(u32, f);
  u32 r = (u + 0x7fffu + ((u >> 16) & 1u)) >> 16;  // RNE
  return (u16)r;
}

// ---------------- conversion ----------------
__global__ void f2bf_kernel(const float* __restrict__ in, u16* __restrict__ out, int n4) {
  int i = blockIdx.x * 256 + threadIdx.x;
  if (i < n4) {
    float4 v = *(const float4*)(in + (size_t)i * 4);
    ushort4 o;
    o.x = f2bf(v.x); o.y = f2bf(v.y); o.z = f2bf(v.z); o.w = f2bf(v.w);
    *(ushort4*)(out + (size_t)i * 4) = o;
  }
}

// ---------------- CSR build ----------------
__global__ void zero_int_kernel(int* p, int n) {
  int i = blockIdx.x * 256 + threadIdx.x;
  if (i < n) p[i] = 0;
}
__global__ void deg_count_kernel(const int* __restrict__ dst, int* __restrict__ degs, int e) {
  int i = blockIdx.x * 256 + threadIdx.x;
  if (i < e) atomicAdd(&degs[dst[i]], 1);
}
__global__ void norm_kernel(const int* __restrict__ degs, float* __restrict__ norm, int n) {
  int i = blockIdx.x * 256 + threadIdx.x;
  if (i < n) norm[i] = rsqrtf(fmaxf((float)degs[i], 1.0f));
}
__global__ void reduce256_kernel(const int* __restrict__ v, int n, int* __restrict__ bsums) {
  __shared__ int s[256];
  int t = threadIdx.x;
  int i = blockIdx.x * 256 + t;
  s[t] = (i < n) ? v[i] : 0;
  __syncthreads();
  for (int st = 128; st > 0; st >>= 1) {
    if (t < st) s[t] += s[t + st];
    __syncthreads();
  }
  if (t == 0) bsums[blockIdx.x] = s[0];
}
__global__ void scan_small_kernel(int* b, int nb) {
  __shared__ int s[256];
  int t = threadIdx.x;
  int orig = (t < nb) ? b[t] : 0;
  s[t] = orig;
  __syncthreads();
  for (int st = 1; st < 256; st <<= 1) {
    int v = (t >= st) ? s[t - st] : 0;
    __syncthreads();
    s[t] += v;
    __syncthreads();
  }
  if (t < nb) b[t] = s[t] - orig;
}
__global__ void scan_final_kernel(const int* __restrict__ degs, const int* __restrict__ boff,
                                  int* __restrict__ out, int n, int total) {
  __shared__ int s[256];
  int t = threadIdx.x;
  int i = blockIdx.x * 256 + t;
  int orig = (i < n) ? degs[i] : 0;
  s[t] = orig;
  __syncthreads();
  for (int st = 1; st < 256; st <<= 1) {
    int v = (t >= st) ? s[t - st] : 0;
    __syncthreads();
    s[t] += v;
    __syncthreads();
  }
  if (i < n) out[i] = boff[blockIdx.x] + s[t] - orig;
  if (i == 0) out[n] = total;
}
__global__ void copy_int_kernel(const int* __restrict__ a, int* __restrict__ b, int n) {
  int i = blockIdx.x * 256 + threadIdx.x;
  if (i < n) b[i] = a[i];
}
__global__ void fill_csr_kernel(const int* __restrict__ esrc, const int* __restrict__ edst,
                                int* __restrict__ cursor, int* __restrict__ csr_src, int e) {
  int i = blockIdx.x * 256 + threadIdx.x;
  if (i < e) {
    int p = atomicAdd(&cursor[edst[i]], 1);
    csr_src[p] = esrc[i];
  }
}

// ---------------- bf16 propagation ----------------
// out[node, :] = norm[node] * sum_e in[src[e], :] * norm[src[e]]  (bf16 in/out, fp32 accum)
__global__ void prop_bf16_kernel(const u16* __restrict__ in, int ldin,
                                 u16* __restrict__ out, int ldout,
                                 const int* __restrict__ off, const int* __restrict__ srcs,
                                 const float* __restrict__ norm, int pairs) {
  int node = blockIdx.x;
  int e0 = off[node], e1 = off[node + 1];
  float nd = norm[node];
  for (int cp = threadIdx.x; cp < pairs; cp += blockDim.x) {
    float a0 = 0.f, a1 = 0.f;
    const u16* base = in + 2 * cp;
    for (int e = e0; e < e1; ++e) {
      int s = srcs[e];
      u32 v = *(const u32*)(base + (size_t)s * ldin);
      float ns = norm[s];
      a0 = fmaf(ns, bf2f((u16)(v & 0xffffu)), a0);
      a1 = fmaf(ns, bf2f((u16)(v >> 16)), a1);
    }
    u32 o = (u32)f2bf(a0 * nd) | ((u32)f2bf(a1 * nd) << 16);
    *(u32*)(out + (size_t)node * ldout + 2 * cp) = o;
  }
}

// ---------------- bf16 MFMA GEMM ----------------
// C[r, colOff..colOff+127] = [A1|A2](r) @ W^T (+bias, act). W: [128][K] row-major bf16.
// Gather mode (gsrc!=null): row r of A = A1[gsrc[r]] for k<K1, A2[gdst[r]] for k>=K1.
// BM=64, BN=128, BK=32. 256 threads = 4 waves (2x2 of 32x64). act: 0 none, 1 ELU, 2 ReLU.
__global__ __launch_bounds__(256) void mfma_gemm_kernel(
    const u16* __restrict__ A1, int lda1, int K1,
    const u16* __restrict__ A2, int lda2, int K2,
    const int* __restrict__ gsrc, const int* __restrict__ gdst,
    const u16* __restrict__ W, const float* __restrict__ bias,
    u16* __restrict__ C, int ldc, int colOff,
    int nrows, int act) {
  // LDS: rows padded to 80B (40 bf16 = 20 uints): 5*16B granules/row -> ~2-way banks on b128
  __shared__ u32 As[64 * 20];
  __shared__ u32 Ws[128 * 20];
  const int tid = threadIdx.x;
  const int brow = blockIdx.x * 64;
  const int K = K1 + K2;

  const int lane = tid & 63;
  const int wv = tid >> 6;
  const int wr = (wv >> 1) * 32;  // wave row base
  const int wc = (wv & 1) * 64;   // wave col base
  const int fr = lane & 15;
  const int fk = (lane >> 4) * 4; // uint offset (4 uints = 8 bf16 of k)

  f32x4 acc[2][4];
#pragma unroll
  for (int m = 0; m < 2; ++m)
#pragma unroll
    for (int n = 0; n < 4; ++n) acc[m][n] = (f32x4){0.f, 0.f, 0.f, 0.f};

  const int sr = tid >> 2, skb = tid & 3;   // A staging: row sr, 16B chunk skb
  const int swc = tid >> 1, skh = tid & 1;  // W staging: col swc, 32B half skh

  for (int kc = 0; kc < K; kc += 32) {
    // A chunk -> regs
    uint4 av = make_uint4(0, 0, 0, 0);
    {
      int grow = brow + sr;
      if (grow < nrows) {
        const u16* p;
        if (gsrc) {
          int node = (kc < K1) ? gsrc[grow] : gdst[grow];
          const u16* base = (kc < K1) ? A1 : A2;
          int ld = (kc < K1) ? lda1 : lda2;
          int kk = (kc < K1) ? kc : kc - K1;
          p = base + (size_t)node * ld + kk + skb * 8;
        } else if (kc < K1) {
          p = A1 + (size_t)grow * lda1 + kc + skb * 8;
        } else {
          p = A2 + (size_t)grow * lda2 + (kc - K1) + skb * 8;
        }
        av = *(const uint4*)p;
      }
    }
    // W chunk -> regs (32B per thread)
    const u16* wp = W + (size_t)swc * K + kc + skh * 16;
    uint4 wv0 = *(const uint4*)wp;
    uint4 wv1 = *(const uint4*)(wp + 8);

    __syncthreads();
    *(uint4*)&As[sr * 20 + skb * 4] = av;
    *(uint4*)&Ws[swc * 20 + skh * 8] = wv0;
    *(uint4*)&Ws[swc * 20 + skh * 8 + 4] = wv1;
    __syncthreads();

    bf16x8 aF0 = *(const bf16x8*)&As[(wr + fr) * 20 + fk];
    bf16x8 aF1 = *(const bf16x8*)&As[(wr + 16 + fr) * 20 + fk];
#pragma unroll
    for (int n = 0; n < 4; ++n) {
      bf16x8 bF = *(const bf16x8*)&Ws[(wc + n * 16 + fr) * 20 + fk];
      acc[0][n] = __builtin_amdgcn_mfma_f32_16x16x32_bf16(aF0, bF, acc[0][n], 0, 0, 0);
      acc[1][n] = __builtin_amdgcn_mfma_f32_16x16x32_bf16(aF1, bF, acc[1][n], 0, 0, 0);
    }
  }

  // epilogue: D lane map col=lane&15, row=(lane>>4)*4+i  [m89]
#pragma unroll
  for (int m = 0; m < 2; ++m) {
#pragma unroll
    for (int n = 0; n < 4; ++n) {
      int ccol = wc + n * 16 + fr;
      float b = bias ? bias[ccol] : 0.f;
#pragma unroll
      for (int i = 0; i < 4; ++i) {
        int row = brow + wr + m * 16 + (lane >> 4) * 4 + i;
        if (row < nrows) {
          float v = acc[m][n][i] + b;
          if (act == 1) v = (v > 0.f) ? v : (expf(v) - 1.f);
          else if (act == 2) v = fmaxf(v, 0.f);
          C[(size_t)row * ldc + colOff + ccol] = f2bf(v);
        }
      }
    }
  }
}

// ---------------- final score ----------------
__global__ void score_kernel(const u16* __restrict__ hidden, const float* __restrict__ p1w,
                             const float* __restrict__ p1b, float* __restrict__ out, int pairs) {
  int pr = blockIdx.x * 4 + (threadIdx.x >> 6);
  int lane = threadIdx.x & 63;
  if (pr >= pairs) return;
  const u16* h = hidden + (size_t)pr * 128;
  float v = bf2f(h[lane]) * p1w[lane] + bf2f(h[lane + 64]) * p1w[lane + 64];
  for (int off = 32; off > 0; off >>= 1) v += __shfl_down(v, off);
  if (lane == 0) out[pr] = 1.f / (1.f + expf(-(v + p1b[0])));
}

// ---------------- host launcher ----------------
extern "C" void kernel_launch(void* const* d_in, const int* in_sizes, int n_in,
                              void* d_out, int out_size, void* d_ws, size_t ws_size,
                              hipStream_t stream) {
  const float* d_sim   = (const float*)d_in[0];
  const float* m_sim   = (const float*)d_in[1];
  const int*   e_src   = (const int*)d_in[2];
  const int*   e_dst   = (const int*)d_in[3];
  const int*   p_src   = (const int*)d_in[4];
  const int*   p_dst   = (const int*)d_in[5];
  const float* d_fc_w  = (const float*)d_in[6];
  const float* d_fc_b  = (const float*)d_in[7];
  const float* m_fc_w  = (const float*)d_in[8];
  const float* m_fc_b  = (const float*)d_in[9];
  const float* l0_w    = (const float*)d_in[10];
  const float* l1_w    = (const float*)d_in[11];
  const float* fc_w    = (const float*)d_in[12];
  const float* d_fc1_w = (const float*)d_in[13];
  const float* d_fc1_b = (const float*)d_in[14];
  const float* m_fc1_w = (const float*)d_in[15];
  const float* m_fc1_b = (const float*)d_in[16];
  const float* p0_w    = (const float*)d_in[17];
  const float* p0_b    = (const float*)d_in[18];
  const float* p1_w    = (const float*)d_in[19];
  const float* p1_b    = (const float*)d_in[20];
  float* out = (float*)d_out;

  const int N = N_NODES, D = D_NODES, M = M_NODES, E = E_EDGES, NP = PAIRS_N;

  // ---- workspace layout (u16 units unless noted)
  const size_t BIG = (size_t)N * 384;  // one [N,384] bf16 buffer
  u16* ws16 = (u16*)d_ws;
  u16* BA = ws16;                    // [N,384]
  u16* BB = BA + BIG;                // [N,384]
  u16* BC = BB + BIG;                // [N,384]
  u16* dsimh = BC + BIG;             // [D,512]
  u16* msimh = dsimh + (size_t)D * 512;   // [M,512]
  u16* wb = msimh + (size_t)M * 512;      // weights bf16
  u16* wb_dfc  = wb;                      // 128*512
  u16* wb_mfc  = wb_dfc  + 65536;
  u16* wb_l0   = wb_mfc  + 65536;         // 3*128*128
  u16* wb_l1   = wb_l0   + 49152;         // 3*128*384
  u16* wb_fc   = wb_l1   + 147456;        // 128*384
  u16* wb_dfc1 = wb_fc   + 49152;         // 128*640
  u16* wb_mfc1 = wb_dfc1 + 81920;
  u16* wb_p0   = wb_mfc1 + 81920;         // 128*256
  u16* wend    = wb_p0   + 32768;
  // align to 4 bytes for float/int section
  size_t off16 = (size_t)(wend - ws16);
  off16 = (off16 + 1) & ~(size_t)1;
  float* normp = (float*)(ws16 + off16);
  int* degs    = (int*)(normp + N);
  int* csr_off = degs + N;           // N+1
  int* cursor  = csr_off + N + 1;
  int* csr_src = cursor + N;         // E
  int* bsums   = csr_src + E;        // <=256

  const int nb = (N + 255) / 256;
  const int eb = (E + 255) / 256;

  // ---- convert sims + weights to bf16
  {
    int n4;
    n4 = D * 512 / 4; f2bf_kernel<<<(n4 + 255) / 256, 256, 0, stream>>>(d_sim, dsimh, n4);
    n4 = M * 512 / 4; f2bf_kernel<<<(n4 + 255) / 256, 256, 0, stream>>>(m_sim + (size_t)D * 512, msimh, n4);
    n4 = 65536 / 4;  f2bf_kernel<<<(n4 + 255) / 256, 256, 0, stream>>>(d_fc_w, wb_dfc, n4);
    f2bf_kernel<<<(n4 + 255) / 256, 256, 0, stream>>>(m_fc_w, wb_mfc, n4);
    n4 = 49152 / 4;  f2bf_kernel<<<(n4 + 255) / 256, 256, 0, stream>>>(l0_w, wb_l0, n4);
    n4 = 147456 / 4; f2bf_kernel<<<(n4 + 255) / 256, 256, 0, stream>>>(l1_w, wb_l1, n4);
    n4 = 49152 / 4;  f2bf_kernel<<<(n4 + 255) / 256, 256, 0, stream>>>(fc_w, wb_fc, n4);
    n4 = 81920 / 4;  f2bf_kernel<<<(n4 + 255) / 256, 256, 0, stream>>>(d_fc1_w, wb_dfc1, n4);
    f2bf_kernel<<<(n4 + 255) / 256, 256, 0, stream>>>(m_fc1_w, wb_mfc1, n4);
    n4 = 32768 / 4;  f2bf_kernel<<<(n4 + 255) / 256, 256, 0, stream>>>(p0_w, wb_p0, n4);
  }

  // ---- degrees, norm, CSR-by-dst
  zero_int_kernel<<<nb, 256, 0, stream>>>(degs, N);
  deg_count_kernel<<<eb, 256, 0, stream>>>(e_dst, degs, E);
  norm_kernel<<<nb, 256, 0, stream>>>(degs, normp, N);
  reduce256_kernel<<<nb, 256, 0, stream>>>(degs, N, bsums);
  scan_small_kernel<<<1, 256, 0, stream>>>(bsums, nb);
  scan_final_kernel<<<nb, 256, 0, stream>>>(degs, bsums, csr_off, N, E);
  copy_int_kernel<<<nb, 256, 0, stream>>>(csr_off, cursor, N);
  fill_csr_kernel<<<eb, 256, 0, stream>>>(e_src, e_dst, cursor, csr_src, E);

  const int GD = (D + 63) / 64, GM = (M + 63) / 64, GN = (N + 63) / 64, GP = (NP + 63) / 64;

  // ---- input projection: Z [N,128] bf16 -> BA (ld 128)
  mfma_gemm_kernel<<<GD, 256, 0, stream>>>(dsimh, 512, 512, nullptr, 0, 0, nullptr, nullptr,
                                           wb_dfc, d_fc_b, BA, 128, 0, D, 0);
  mfma_gemm_kernel<<<GM, 256, 0, stream>>>(msimh, 512, 512, nullptr, 0, 0, nullptr, nullptr,
                                           wb_mfc, m_fc_b, BA + (size_t)D * 128, 128, 0, M, 0);

  // ---- MixHop L0: Z(BA,128) -> BB [N,384]
  mfma_gemm_kernel<<<GN, 256, 0, stream>>>(BA, 128, 128, nullptr, 0, 0, nullptr, nullptr,
                                           wb_l0 + 0 * 16384, nullptr, BB, 384, 0, N, 0);
  prop_bf16_kernel<<<N, 64, 0, stream>>>(BA, 128, BC, 128, csr_off, csr_src, normp, 64);   // P1
  mfma_gemm_kernel<<<GN, 256, 0, stream>>>(BC, 128, 128, nullptr, 0, 0, nullptr, nullptr,
                                           wb_l0 + 1 * 16384, nullptr, BB, 384, 128, N, 0);
  prop_bf16_kernel<<<N, 64, 0, stream>>>(BC, 128, BA, 128, csr_off, csr_src, normp, 64);   // P2 (Z dead)
  mfma_gemm_kernel<<<GN, 256, 0, stream>>>(BA, 128, 128, nullptr, 0, 0, nullptr, nullptr,
                                           wb_l0 + 2 * 16384, nullptr, BB, 384, 256, N, 0);

  // ---- MixHop L1: BB [N,384] -> BC [N,384]
  mfma_gemm_kernel<<<GN, 256, 0, stream>>>(BB, 384, 384, nullptr, 0, 0, nullptr, nullptr,
                                           wb_l1 + 0 * 49152, nullptr, BC, 384, 0, N, 0);
  prop_bf16_kernel<<<N, 192, 0, stream>>>(BB, 384, BA, 384, csr_off, csr_src, normp, 192); // P1' = A@BB
  mfma_gemm_kernel<<<GN, 256, 0, stream>>>(BA, 384, 384, nullptr, 0, 0, nullptr, nullptr,
                                           wb_l1 + 1 * 49152, nullptr, BC, 384, 128, N, 0);
  // commutation: out2 = A (P1' W2^T): project first (Y2 -> BB region, ld 128), then 128-wide prop
  mfma_gemm_kernel<<<GN, 256, 0, stream>>>(BA, 384, 384, nullptr, 0, 0, nullptr, nullptr,
                                           wb_l1 + 2 * 49152, nullptr, BB, 128, 0, N, 0);
  prop_bf16_kernel<<<N, 64, 0, stream>>>(BB, 128, BC + 256, 384, csr_off, csr_src, normp, 64);

  // ---- fc: BC [N,384] -> feats2 (BB, ld 128)
  mfma_gemm_kernel<<<GN, 256, 0, stream>>>(BC, 384, 384, nullptr, 0, 0, nullptr, nullptr,
                                           wb_fc, nullptr, BB, 128, 0, N, 0);

  // ---- fc1 (+ELU): h -> BA (ld 128)
  mfma_gemm_kernel<<<GD, 256, 0, stream>>>(BB, 128, 128, dsimh, 512, 512, nullptr, nullptr,
                                           wb_dfc1, d_fc1_b, BA, 128, 0, D, 1);
  mfma_gemm_kernel<<<GM, 256, 0, stream>>>(BB + (size_t)D * 128, 128, 128, msimh, 512, 512, nullptr, nullptr,
                                           wb_mfc1, m_fc1_b, BA + (size_t)D * 128, 128, 0, M, 1);

  // ---- predictor p0 (gathered concat) + ReLU: hidden [NP,128] -> BC
  mfma_gemm_kernel<<<GP, 256, 0, stream>>>(BA, 128, 128, BA, 128, 128, p_src, p_dst,
                                           wb_p0, p0_b, BC, 128, 0, NP, 2);

  // ---- final dot + sigmoid
  score_kernel<<<(NP + 3) / 4, 256, 0, stream>>>(BC, p1_w, p1_b, out, NP);

  (void)in_sizes; (void)n_in; (void)out_size; (void)ws_size;
}

// Round 3
// 560.679 us; speedup vs baseline: 2.8321x; 1.2134x over previous
//
#include <hip/hip_runtime.h>
#include <cstddef>
#include <cstdint>

#define N_NODES 50000
#define D_NODES 20000
#define M_NODES 30000
#define E_EDGES 800000
#define PAIRS_N 100000

typedef unsigned short u16;
typedef unsigned int u32;
typedef short bf16x8 __attribute__((ext_vector_type(8)));
typedef float f32x4 __attribute__((ext_vector_type(4)));

__device__ __forceinline__ float bf2f(u16 u) {
  u32 v = ((u32)u) << 16;
  return __builtin_bit_cast(float, v);
}
__device__ __forceinline__ u16 f2bf(float f) {
  u32 u = __builtin_bit_cast(u32, f);
  u32 r = (u + 0x7fffu + ((u >> 16) & 1u)) >> 16;  // RNE
  return (u16)r;
}
__device__ __forceinline__ u32 pk2(float x, float y) {
  return (u32)f2bf(x) | ((u32)f2bf(y) << 16);
}

// ---------------- fused weight conversion (all 8 weight mats, one launch) ----
__global__ void wconv_kernel(const float* s0, const float* s1, const float* s2,
                             const float* s3, const float* s4, const float* s5,
                             const float* s6, const float* s7,
                             u16* d0, u16* d1, u16* d2, u16* d3,
                             u16* d4, u16* d5, u16* d6, u16* d7) {
  int i = blockIdx.x * 256 + threadIdx.x;  // quad index
  const float* s; u16* d; int l;
  if      (i <  16384) { s = s0; d = d0; l = i; }
  else if (i <  32768) { s = s1; d = d1; l = i - 16384; }
  else if (i <  45056) { s = s2; d = d2; l = i - 32768; }
  else if (i <  81920) { s = s3; d = d3; l = i - 45056; }
  else if (i <  94208) { s = s4; d = d4; l = i - 81920; }
  else if (i < 114688) { s = s5; d = d5; l = i - 94208; }
  else if (i < 135168) { s = s6; d = d6; l = i - 114688; }
  else if (i < 143360) { s = s7; d = d7; l = i - 135168; }
  else return;
  float4 v = *(const float4*)(s + (size_t)l * 4);
  ushort4 o;
  o.x = f2bf(v.x); o.y = f2bf(v.y); o.z = f2bf(v.z); o.w = f2bf(v.w);
  *(ushort4*)(d + (size_t)l * 4) = o;
}

// ---------------- CSR build ----------------
__global__ void deg_count_kernel(const int* __restrict__ dst, int* __restrict__ degs, int e) {
  int i = blockIdx.x * 256 + threadIdx.x;
  if (i < e) atomicAdd(&degs[dst[i]], 1);
}
__global__ void norm_reduce_kernel(const int* __restrict__ degs, float* __restrict__ norm,
                                   int n, int* __restrict__ bsums) {
  __shared__ int s[256];
  int t = threadIdx.x;
  int i = blockIdx.x * 256 + t;
  int d = (i < n) ? degs[i] : 0;
  if (i < n) norm[i] = rsqrtf(fmaxf((float)d, 1.0f));
  s[t] = d;
  __syncthreads();
  for (int st = 128; st > 0; st >>= 1) {
    if (t < st) s[t] += s[t + st];
    __syncthreads();
  }
  if (t == 0) bsums[blockIdx.x] = s[0];
}
__global__ void scan_small_kernel(int* b, int nb) {
  __shared__ int s[256];
  int t = threadIdx.x;
  int orig = (t < nb) ? b[t] : 0;
  s[t] = orig;
  __syncthreads();
  for (int st = 1; st < 256; st <<= 1) {
    int v = (t >= st) ? s[t - st] : 0;
    __syncthreads();
    s[t] += v;
    __syncthreads();
  }
  if (t < nb) b[t] = s[t] - orig;
}
__global__ void scan_final_kernel(const int* __restrict__ degs, const int* __restrict__ boff,
                                  int* __restrict__ out, int* __restrict__ cursor,
                                  int n, int total) {
  __shared__ int s[256];
  int t = threadIdx.x;
  int i = blockIdx.x * 256 + t;
  int orig = (i < n) ? degs[i] : 0;
  s[t] = orig;
  __syncthreads();
  for (int st = 1; st < 256; st <<= 1) {
    int v = (t >= st) ? s[t - st] : 0;
    __syncthreads();
    s[t] += v;
    __syncthreads();
  }
  if (i < n) {
    int v = boff[blockIdx.x] + s[t] - orig;
    out[i] = v;
    cursor[i] = v;
  }
  if (i == 0) out[n] = total;
}
__global__ void fill_csr_kernel(const int* __restrict__ esrc, const int* __restrict__ edst,
                                int* __restrict__ cursor, int* __restrict__ csr_src, int e) {
  int i = blockIdx.x * 256 + threadIdx.x;
  if (i < e) {
    int p = atomicAdd(&cursor[edst[i]], 1);
    csr_src[p] = esrc[i];
  }
}

// ---------------- bf16 propagation ----------------
// blockDim = 2*pairs. Two thread-groups split the edge list (LDS combine); 4x edge unroll.
// out: cp < split -> out0[node*ldout0 + 2cp]; else out1[node*ldout1 + 2(cp-split)].
__global__ void prop_kernel(const u16* __restrict__ in, int ldin,
                            u16* __restrict__ out0, int ldout0,
                            u16* __restrict__ out1, int ldout1, int split,
                            const int* __restrict__ off, const int* __restrict__ srcs,
                            const float* __restrict__ norm, int pairs) {
  __shared__ float red[256];
  int node = blockIdx.x;
  int tid = threadIdx.x;
  int g = (tid >= pairs) ? 1 : 0;
  int cp = tid - g * pairs;
  int e0 = off[node], e1 = off[node + 1];
  int em = e0 + ((e1 - e0) >> 1);
  int lo = g ? em : e0;
  int hi = g ? e1 : em;
  float a0 = 0.f, a1 = 0.f;
  const u16* base = in + 2 * cp;
  int e = lo;
  for (; e + 4 <= hi; e += 4) {
    int s0 = srcs[e], s1 = srcs[e + 1], s2 = srcs[e + 2], s3 = srcs[e + 3];
    u32 v0 = *(const u32*)(base + (size_t)s0 * ldin);
    u32 v1 = *(const u32*)(base + (size_t)s1 * ldin);
    u32 v2 = *(const u32*)(base + (size_t)s2 * ldin);
    u32 v3 = *(const u32*)(base + (size_t)s3 * ldin);
    float n0 = norm[s0], n1 = norm[s1], n2 = norm[s2], n3 = norm[s3];
    a0 = fmaf(n0, bf2f((u16)v0), a0); a1 = fmaf(n0, bf2f((u16)(v0 >> 16)), a1);
    a0 = fmaf(n1, bf2f((u16)v1), a0); a1 = fmaf(n1, bf2f((u16)(v1 >> 16)), a1);
    a0 = fmaf(n2, bf2f((u16)v2), a0); a1 = fmaf(n2, bf2f((u16)(v2 >> 16)), a1);
    a0 = fmaf(n3, bf2f((u16)v3), a0); a1 = fmaf(n3, bf2f((u16)(v3 >> 16)), a1);
  }
  for (; e < hi; ++e) {
    int s = srcs[e];
    u32 v = *(const u32*)(base + (size_t)s * ldin);
    float ns = norm[s];
    a0 = fmaf(ns, bf2f((u16)v), a0);
    a1 = fmaf(ns, bf2f((u16)(v >> 16)), a1);
  }
  if (g) { red[cp * 2] = a0; red[cp * 2 + 1] = a1; }
  __syncthreads();
  if (!g) {
    a0 += red[cp * 2];
    a1 += red[cp * 2 + 1];
    float nd = norm[node];
    u32 o = pk2(a0 * nd, a1 * nd);
    if (cp < split) *(u32*)(out0 + (size_t)node * ldout0 + 2 * cp) = o;
    else            *(u32*)(out1 + (size_t)node * ldout1 + 2 * (cp - split)) = o;
  }
}

// ---------------- bf16 MFMA GEMM (BK=64, XOR-swizzled LDS) ----------------
// C[r, colOff..colOff+127] = [A1|A2](r) @ W^T (+bias, act). W: [128][K] bf16 row-major.
// A segments may be fp32 (converted in staging). Gather mode via gsrc/gdst.
// BM=64, BN=128, BK=64. 256 threads = 4 waves (2x2 of 32x64). act: 0 none, 1 ELU, 2 ReLU.
__global__ __launch_bounds__(256) void mfma_gemm_kernel(
    const void* __restrict__ A1v, int lda1, int K1, int a1f32,
    const void* __restrict__ A2v, int lda2, int K2, int a2f32,
    const int* __restrict__ gsrc, const int* __restrict__ gdst,
    const u16* __restrict__ W, const float* __restrict__ bias,
    u16* __restrict__ C, int ldc, int colOff, int nrows, int act) {
  __shared__ u32 As[64 * 32];    // row-linear, granule ^= (row&7)
  __shared__ u32 Ws[128 * 32];
  const int tid = threadIdx.x;
  const int brow = blockIdx.x * 64;
  const int K = K1 + K2;
  const int lane = tid & 63;
  const int wv = tid >> 6;
  const int wr = (wv >> 1) * 32;
  const int wc = (wv & 1) * 64;
  const int fr = lane & 15;
  const int fg = lane >> 4;      // k-granule selector (4 u32 each)

  f32x4 acc[2][4];
#pragma unroll
  for (int m = 0; m < 2; ++m)
#pragma unroll
    for (int n = 0; n < 4; ++n) acc[m][n] = (f32x4){0.f, 0.f, 0.f, 0.f};

  const int sr = tid >> 2, sk = tid & 3;     // A staging: row, 16-elem chunk
  const int swc = tid >> 1, sh = tid & 1;    // W staging: col, 32-elem half
  const int prow = (brow + sr < nrows) ? (brow + sr) : (nrows - 1);

  for (int kc = 0; kc < K; kc += 64) {
    // ---- A chunk -> regs (16 bf16 per thread)
    uint4 qa0, qa1;
    {
      bool seg1 = kc < K1;
      int kk = seg1 ? kc : kc - K1;
      const void* Av = seg1 ? A1v : A2v;
      int ld = seg1 ? lda1 : lda2;
      int isf = seg1 ? a1f32 : a2f32;
      int row = gsrc ? (seg1 ? gsrc[prow] : gdst[prow]) : prow;
      if (isf) {
        const float* p = (const float*)Av + (size_t)row * ld + kk + sk * 16;
        float4 f0 = ((const float4*)p)[0];
        float4 f1 = ((const float4*)p)[1];
        float4 f2 = ((const float4*)p)[2];
        float4 f3 = ((const float4*)p)[3];
        qa0 = make_uint4(pk2(f0.x, f0.y), pk2(f0.z, f0.w), pk2(f1.x, f1.y), pk2(f1.z, f1.w));
        qa1 = make_uint4(pk2(f2.x, f2.y), pk2(f2.z, f2.w), pk2(f3.x, f3.y), pk2(f3.z, f3.w));
      } else {
        const u16* p = (const u16*)Av + (size_t)row * ld + kk + sk * 16;
        qa0 = *(const uint4*)p;
        qa1 = *(const uint4*)(p + 8);
      }
    }
    // ---- W chunk -> regs (32 bf16 per thread)
    const u16* wp = W + (size_t)swc * K + kc + sh * 32;
    uint4 qw0 = *(const uint4*)(wp);
    uint4 qw1 = *(const uint4*)(wp + 8);
    uint4 qw2 = *(const uint4*)(wp + 16);
    uint4 qw3 = *(const uint4*)(wp + 24);

    __syncthreads();
    *(uint4*)&As[sr * 32 + ((2 * sk)     ^ (sr & 7)) * 4] = qa0;
    *(uint4*)&As[sr * 32 + ((2 * sk + 1) ^ (sr & 7)) * 4] = qa1;
    *(uint4*)&Ws[swc * 32 + ((sh * 4 + 0) ^ (swc & 7)) * 4] = qw0;
    *(uint4*)&Ws[swc * 32 + ((sh * 4 + 1) ^ (swc & 7)) * 4] = qw1;
    *(uint4*)&Ws[swc * 32 + ((sh * 4 + 2) ^ (swc & 7)) * 4] = qw2;
    *(uint4*)&Ws[swc * 32 + ((sh * 4 + 3) ^ (swc & 7)) * 4] = qw3;
    __syncthreads();

#pragma unroll
    for (int kk2 = 0; kk2 < 2; ++kk2) {
      int gix = kk2 * 4 + fg;
      int r0 = wr + fr, r1 = wr + 16 + fr;
      bf16x8 aF0 = *(const bf16x8*)&As[r0 * 32 + (gix ^ (r0 & 7)) * 4];
      bf16x8 aF1 = *(const bf16x8*)&As[r1 * 32 + (gix ^ (r1 & 7)) * 4];
#pragma unroll
      for (int n = 0; n < 4; ++n) {
        int cr = wc + n * 16 + fr;
        bf16x8 bF = *(const bf16x8*)&Ws[cr * 32 + (gix ^ (cr & 7)) * 4];
        acc[0][n] = __builtin_amdgcn_mfma_f32_16x16x32_bf16(aF0, bF, acc[0][n], 0, 0, 0);
        acc[1][n] = __builtin_amdgcn_mfma_f32_16x16x32_bf16(aF1, bF, acc[1][n], 0, 0, 0);
      }
    }
  }

  // ---- epilogue: D lane map col=lane&15, row=(lane>>4)*4+i  [m89]
#pragma unroll
  for (int m = 0; m < 2; ++m) {
#pragma unroll
    for (int n = 0; n < 4; ++n) {
      int ccol = wc + n * 16 + fr;
      float b = bias ? bias[ccol] : 0.f;
#pragma unroll
      for (int i = 0; i < 4; ++i) {
        int row = brow + wr + m * 16 + (lane >> 4) * 4 + i;
        if (row < nrows) {
          float v = acc[m][n][i] + b;
          if (act == 1) v = (v > 0.f) ? v : (expf(v) - 1.f);
          else if (act == 2) v = fmaxf(v, 0.f);
          C[(size_t)row * ldc + colOff + ccol] = f2bf(v);
        }
      }
    }
  }
}

// ---------------- final score ----------------
__global__ void score_kernel(const u16* __restrict__ hidden, const float* __restrict__ p1w,
                             const float* __restrict__ p1b, float* __restrict__ out, int pairs) {
  int pr = blockIdx.x * 4 + (threadIdx.x >> 6);
  int lane = threadIdx.x & 63;
  if (pr >= pairs) return;
  const u16* h = hidden + (size_t)pr * 128;
  float v = bf2f(h[lane]) * p1w[lane] + bf2f(h[lane + 64]) * p1w[lane + 64];
  for (int off = 32; off > 0; off >>= 1) v += __shfl_down(v, off);
  if (lane == 0) out[pr] = 1.f / (1.f + expf(-(v + p1b[0])));
}

// ---------------- host launcher ----------------
extern "C" void kernel_launch(void* const* d_in, const int* in_sizes, int n_in,
                              void* d_out, int out_size, void* d_ws, size_t ws_size,
                              hipStream_t stream) {
  const float* d_sim   = (const float*)d_in[0];
  const float* m_sim   = (const float*)d_in[1];
  const int*   e_src   = (const int*)d_in[2];
  const int*   e_dst   = (const int*)d_in[3];
  const int*   p_src   = (const int*)d_in[4];
  const int*   p_dst   = (const int*)d_in[5];
  const float* d_fc_w  = (const float*)d_in[6];
  const float* d_fc_b  = (const float*)d_in[7];
  const float* m_fc_w  = (const float*)d_in[8];
  const float* m_fc_b  = (const float*)d_in[9];
  const float* l0_w    = (const float*)d_in[10];
  const float* l1_w    = (const float*)d_in[11];
  const float* fc_w    = (const float*)d_in[12];
  const float* d_fc1_w = (const float*)d_in[13];
  const float* d_fc1_b = (const float*)d_in[14];
  const float* m_fc1_w = (const float*)d_in[15];
  const float* m_fc1_b = (const float*)d_in[16];
  const float* p0_w    = (const float*)d_in[17];
  const float* p0_b    = (const float*)d_in[18];
  const float* p1_w    = (const float*)d_in[19];
  const float* p1_b    = (const float*)d_in[20];
  float* out = (float*)d_out;

  const int N = N_NODES, D = D_NODES, M = M_NODES, E = E_EDGES, NP = PAIRS_N;

  // ---- workspace layout
  const size_t BIG = (size_t)N * 384;
  u16* ws16 = (u16*)d_ws;
  u16* BA = ws16;                    // [N,384]
  u16* BB = BA + BIG;
  u16* BC = BB + BIG;
  u16* wb = BC + BIG;                // bf16 weights, 573440 u16
  u16* wb_dfc  = wb;                 // 65536
  u16* wb_mfc  = wb_dfc  + 65536;
  u16* wb_l0   = wb_mfc  + 65536;    // 49152
  u16* wb_l1   = wb_l0   + 49152;    // 147456
  u16* wb_fc   = wb_l1   + 147456;   // 49152
  u16* wb_dfc1 = wb_fc   + 49152;    // 81920
  u16* wb_mfc1 = wb_dfc1 + 81920;    // 81920
  u16* wb_p0   = wb_mfc1 + 81920;    // 32768
  u16* wend    = wb_p0   + 32768;
  size_t off16 = (size_t)(wend - ws16);
  off16 = (off16 + 1) & ~(size_t)1;
  float* normp = (float*)(ws16 + off16);
  int* degs    = (int*)(normp + N);
  int* csr_off = degs + N;           // N+1
  int* cursor  = csr_off + N + 1;    // N
  int* csr_src = cursor + N;         // E
  int* bsums   = csr_src + E;        // <=256

  const int nb = (N + 255) / 256;
  const int eb = (E + 255) / 256;

  // ---- weights -> bf16 (one launch)
  wconv_kernel<<<560, 256, 0, stream>>>(d_fc_w, m_fc_w, l0_w, l1_w, fc_w, d_fc1_w, m_fc1_w, p0_w,
                                        wb_dfc, wb_mfc, wb_l0, wb_l1, wb_fc, wb_dfc1, wb_mfc1, wb_p0);

  // ---- degrees, norm, CSR-by-dst
  hipMemsetAsync(degs, 0, (size_t)N * 4, stream);
  deg_count_kernel<<<eb, 256, 0, stream>>>(e_dst, degs, E);
  norm_reduce_kernel<<<nb, 256, 0, stream>>>(degs, normp, N, bsums);
  scan_small_kernel<<<1, 256, 0, stream>>>(bsums, nb);
  scan_final_kernel<<<nb, 256, 0, stream>>>(degs, bsums, csr_off, cursor, N, E);
  fill_csr_kernel<<<eb, 256, 0, stream>>>(e_src, e_dst, cursor, csr_src, E);

  const int GD = (D + 63) / 64, GM = (M + 63) / 64, GN = (N + 63) / 64, GP = (NP + 63) / 64;

  // ---- input projection (fp32 sims read directly): Z -> BC (ld 128)
  mfma_gemm_kernel<<<GD, 256, 0, stream>>>(d_sim, 512, 512, 1, nullptr, 0, 0, 0, nullptr, nullptr,
                                           wb_dfc, d_fc_b, BC, 128, 0, D, 0);
  mfma_gemm_kernel<<<GM, 256, 0, stream>>>(m_sim + (size_t)D * 512, 512, 512, 1, nullptr, 0, 0, 0,
                                           nullptr, nullptr, wb_mfc, m_fc_b,
                                           BC + (size_t)D * 128, 128, 0, M, 0);

  // ---- MixHop L0: Z(BC) -> BB [N,384]
  mfma_gemm_kernel<<<GN, 256, 0, stream>>>(BC, 128, 128, 0, nullptr, 0, 0, 0, nullptr, nullptr,
                                           wb_l0 + 0 * 16384, nullptr, BB, 384, 0, N, 0);
  prop_kernel<<<N, 128, 0, stream>>>(BC, 128, BA, 128, nullptr, 0, 64, csr_off, csr_src, normp, 64);
  mfma_gemm_kernel<<<GN, 256, 0, stream>>>(BA, 128, 128, 0, nullptr, 0, 0, 0, nullptr, nullptr,
                                           wb_l0 + 1 * 16384, nullptr, BB, 384, 128, N, 0);
  prop_kernel<<<N, 128, 0, stream>>>(BA, 128, BC, 128, nullptr, 0, 64, csr_off, csr_src, normp, 64);
  mfma_gemm_kernel<<<GN, 256, 0, stream>>>(BC, 128, 128, 0, nullptr, 0, 0, 0, nullptr, nullptr,
                                           wb_l0 + 2 * 16384, nullptr, BB, 384, 256, N, 0);

  // ---- MixHop L1 (fully commuted): BB [N,384] -> BC [N,384]
  mfma_gemm_kernel<<<GN, 256, 0, stream>>>(BB, 384, 384, 0, nullptr, 0, 0, 0, nullptr, nullptr,
                                           wb_l1 + 0 * 49152, nullptr, BC, 384, 0, N, 0);
  mfma_gemm_kernel<<<GN, 256, 0, stream>>>(BB, 384, 384, 0, nullptr, 0, 0, 0, nullptr, nullptr,
                                           wb_l1 + 1 * 49152, nullptr, BA, 256, 0, N, 0);
  mfma_gemm_kernel<<<GN, 256, 0, stream>>>(BB, 384, 384, 0, nullptr, 0, 0, 0, nullptr, nullptr,
                                           wb_l1 + 2 * 49152, nullptr, BA, 256, 128, N, 0);
  // 256-wide prop: half0 -> BC cols 128..255, half1 -> BB (ld 128)
  prop_kernel<<<N, 256, 0, stream>>>(BA, 256, BC + 128, 384, BB, 128, 64, csr_off, csr_src, normp, 128);
  // second hop of the W2 path: BB -> BC cols 256..383
  prop_kernel<<<N, 128, 0, stream>>>(BB, 128, BC + 256, 384, nullptr, 0, 64, csr_off, csr_src, normp, 64);

  // ---- fc: BC [N,384] -> BA (ld 128)
  mfma_gemm_kernel<<<GN, 256, 0, stream>>>(BC, 384, 384, 0, nullptr, 0, 0, 0, nullptr, nullptr,
                                           wb_fc, nullptr, BA, 128, 0, N, 0);

  // ---- fc1 (+ELU): [feats | sims(fp32)] -> h in BB (ld 128)
  mfma_gemm_kernel<<<GD, 256, 0, stream>>>(BA, 128, 128, 0, d_sim, 512, 512, 1, nullptr, nullptr,
                                           wb_dfc1, d_fc1_b, BB, 128, 0, D, 1);
  mfma_gemm_kernel<<<GM, 256, 0, stream>>>(BA + (size_t)D * 128, 128, 128, 0,
                                           m_sim + (size_t)D * 512, 512, 512, 1, nullptr, nullptr,
                                           wb_mfc1, m_fc1_b, BB + (size_t)D * 128, 128, 0, M, 1);

  // ---- predictor p0 (gathered concat) + ReLU: hidden [NP,128] -> BC
  mfma_gemm_kernel<<<GP, 256, 0, stream>>>(BB, 128, 128, 0, BB, 128, 128, 0, p_src, p_dst,
                                           wb_p0, p0_b, BC, 128, 0, NP, 2);

  // ---- final dot + sigmoid
  score_kernel<<<(NP + 3) / 4, 256, 0, stream>>>(BC, p1_w, p1_b, out, NP);

  (void)in_sizes; (void)n_in; (void)out_size; (void)ws_size;
}

// Round 4
// 434.008 us; speedup vs baseline: 3.6587x; 1.2919x over previous
//
#include <hip/hip_runtime.h>
#include <cstddef>
#include <cstdint>

#define N_NODES 50000
#define D_NODES 20000
#define M_NODES 30000
#define E_EDGES 800000
#define PAIRS_N 100000

typedef unsigned short u16;
typedef unsigned int u32;
typedef short bf16x8 __attribute__((ext_vector_type(8)));
typedef float f32x4 __attribute__((ext_vector_type(4)));

__device__ __forceinline__ float bf2f(u16 u) {
  u32 v = ((u32)u) << 16;
  return __builtin_bit_cast(float, v);
}
__device__ __forceinline__ u16 f2bf(float f) {
  u32 u = __builtin_bit_cast(u32, f);
  u32 r = (u + 0x7fffu + ((u >> 16) & 1u)) >> 16;  // RNE
  return (u16)r;
}
__device__ __forceinline__ u32 pk2(float x, float y) {
  return (u32)f2bf(x) | ((u32)f2bf(y) << 16);
}

// ---------------- weight conversion (5 mats -> bf16, one launch) ----------------
__global__ void wconv_kernel(const float* s0, const float* s1, const float* s2,
                             const float* s3, const float* s4,
                             u16* d0, u16* d1, u16* d2, u16* d3, u16* d4) {
  int i = blockIdx.x * 256 + threadIdx.x;  // quad index
  const float* s; u16* d; int l;
  if      (i < 16384) { s = s0; d = d0; l = i; }
  else if (i < 32768) { s = s1; d = d1; l = i - 16384; }
  else if (i < 53248) { s = s2; d = d2; l = i - 32768; }
  else if (i < 73728) { s = s3; d = d3; l = i - 53248; }
  else if (i < 81920) { s = s4; d = d4; l = i - 73728; }
  else return;
  float4 v = *(const float4*)(s + (size_t)l * 4);
  ushort4 o;
  o.x = f2bf(v.x); o.y = f2bf(v.y); o.z = f2bf(v.z); o.w = f2bf(v.w);
  *(ushort4*)(d + (size_t)l * 4) = o;
}

// ---------------- weight combine: G_k = sum_{p+j=k} fc_p * W'_pj * W_j ----------
// Tmp_pj = W'_pj @ W_j   (fp32 [128][128])
__global__ void wcomb1_kernel(const float* __restrict__ l1w, const float* __restrict__ l0w,
                              float* __restrict__ Tmp) {
  int pj = blockIdx.x;          // 0..8
  int p = pj / 3, j = pj % 3;
  int o = blockIdx.y;           // 0..127
  int i = threadIdx.x;          // 0..127
  const float* wp = l1w + (size_t)p * 49152 + (size_t)o * 384 + 128 * j;
  const float* wj = l0w + (size_t)j * 16384 + i;
  float acc = 0.f;
#pragma unroll 4
  for (int t = 0; t < 128; ++t) acc += wp[t] * wj[(size_t)t * 128];
  Tmp[(size_t)pj * 16384 + (size_t)o * 128 + i] = acc;
}
// G[of][640]: col-block k = sum_p fc_p @ Tmp_{p,k-p}, bf16 output
__global__ void wcomb2_kernel(const float* __restrict__ fcw, const float* __restrict__ Tmp,
                              u16* __restrict__ G) {
  int k = blockIdx.x;           // 0..4
  int of = blockIdx.y;          // 0..127
  int i = threadIdx.x;          // 0..127
  float acc = 0.f;
  int plo = (k > 2) ? (k - 2) : 0;
  int phi = (k < 2) ? k : 2;
  for (int p = plo; p <= phi; ++p) {
    int j = k - p;
    const float* fp = fcw + (size_t)of * 384 + 128 * p;
    const float* tp = Tmp + (size_t)(p * 3 + j) * 16384 + i;
#pragma unroll 4
    for (int t = 0; t < 128; ++t) acc += fp[t] * tp[(size_t)t * 128];
  }
  G[(size_t)of * 640 + 128 * k + i] = f2bf(acc);
}

// ---------------- CSR build ----------------
__global__ void deg_count_kernel(const int* __restrict__ dst, int* __restrict__ degs, int e) {
  int i = blockIdx.x * 256 + threadIdx.x;
  if (i < e) atomicAdd(&degs[dst[i]], 1);
}
__global__ void norm_reduce_kernel(const int* __restrict__ degs, float* __restrict__ norm,
                                   int n, int* __restrict__ bsums) {
  __shared__ int s[256];
  int t = threadIdx.x;
  int i = blockIdx.x * 256 + t;
  int d = (i < n) ? degs[i] : 0;
  if (i < n) norm[i] = rsqrtf(fmaxf((float)d, 1.0f));
  s[t] = d;
  __syncthreads();
  for (int st = 128; st > 0; st >>= 1) {
    if (t < st) s[t] += s[t + st];
    __syncthreads();
  }
  if (t == 0) bsums[blockIdx.x] = s[0];
}
__global__ void scan_small_kernel(int* b, int nb) {
  __shared__ int s[256];
  int t = threadIdx.x;
  int orig = (t < nb) ? b[t] : 0;
  s[t] = orig;
  __syncthreads();
  for (int st = 1; st < 256; st <<= 1) {
    int v = (t >= st) ? s[t - st] : 0;
    __syncthreads();
    s[t] += v;
    __syncthreads();
  }
  if (t < nb) b[t] = s[t] - orig;
}
__global__ void scan_final_kernel(const int* __restrict__ degs, const int* __restrict__ boff,
                                  int* __restrict__ out, int* __restrict__ cursor,
                                  int n, int total) {
  __shared__ int s[256];
  int t = threadIdx.x;
  int i = blockIdx.x * 256 + t;
  int orig = (i < n) ? degs[i] : 0;
  s[t] = orig;
  __syncthreads();
  for (int st = 1; st < 256; st <<= 1) {
    int v = (t >= st) ? s[t - st] : 0;
    __syncthreads();
    s[t] += v;
    __syncthreads();
  }
  if (i < n) {
    int v = boff[blockIdx.x] + s[t] - orig;
    out[i] = v;
    cursor[i] = v;
  }
  if (i == 0) out[n] = total;
}
__global__ void fill_csr_kernel(const int* __restrict__ esrc, const int* __restrict__ edst,
                                int* __restrict__ cursor, int* __restrict__ csr_src, int e) {
  int i = blockIdx.x * 256 + threadIdx.x;
  if (i < e) {
    int p = atomicAdd(&cursor[edst[i]], 1);
    csr_src[p] = esrc[i];
  }
}

// ---------------- 128-wide propagation on pre-scaled input ----------------
// in (scaled by norm, ld 128). outu[node*ldu + cOff + c] = nd * sum; outs = nd^2 * sum.
// block = 128 thr = 4 groups x 32 lanes; lane covers 4 channels (8B loads).
__global__ void prop128_kernel(const u16* __restrict__ in,
                               u16* __restrict__ outu, int ldu, int cOff,
                               u16* __restrict__ outs,
                               const int* __restrict__ off, const int* __restrict__ srcs,
                               const float* __restrict__ norm) {
  __shared__ float red[4][128];
  const int node = blockIdx.x;
  const int tid = threadIdx.x;
  const int g = tid >> 5, lane = tid & 31;
  const int e0 = off[node], e1 = off[node + 1];
  const int cnt = e1 - e0;
  const int lo = e0 + ((cnt * g) >> 2);
  const int hi = e0 + ((cnt * (g + 1)) >> 2);
  float a0 = 0.f, a1 = 0.f, a2 = 0.f, a3 = 0.f;
  const u16* basec = in + (lane << 2);
  for (int base = lo; base < hi; base += 32) {
    int nE = hi - base; if (nE > 32) nE = 32;
    int myE = srcs[base + ((lane < nE) ? lane : (nE - 1))];
#pragma unroll 4
    for (int i = 0; i < nE; ++i) {
      int s = __builtin_amdgcn_readlane(myE, i);
      uint2 v = *(const uint2*)(basec + ((size_t)s << 7));
      a0 += bf2f((u16)v.x); a1 += bf2f((u16)(v.x >> 16));
      a2 += bf2f((u16)v.y); a3 += bf2f((u16)(v.y >> 16));
    }
  }
  float* rg = red[g];
  rg[(lane << 2) + 0] = a0; rg[(lane << 2) + 1] = a1;
  rg[(lane << 2) + 2] = a2; rg[(lane << 2) + 3] = a3;
  __syncthreads();
  if (tid < 64) {
    int c0 = tid << 1;
    float s0 = red[0][c0] + red[1][c0] + red[2][c0] + red[3][c0];
    float s1 = red[0][c0 + 1] + red[1][c0 + 1] + red[2][c0 + 1] + red[3][c0 + 1];
    float nd = norm[node];
    *(u32*)(outu + (size_t)node * ldu + cOff + c0) = pk2(s0 * nd, s1 * nd);
    if (outs) {
      float nd2 = nd * nd;
      *(u32*)(outs + ((size_t)node << 7) + c0) = pk2(s0 * nd2, s1 * nd2);
    }
  }
}

// ---------------- bf16 MFMA GEMM (BK=64, XOR-swizzled LDS, segmented, dual-out) ----
// Blocks >= splitB use segment b (A1b/A2b/Wb/biasb), rows start at rowD.
// Gather mode via gsrc/gdst (uses segment-a pointers). act: 0 none, 1 ELU, 2 ReLU.
__global__ __launch_bounds__(256) void mfma_gemm_kernel(
    const void* __restrict__ A1a, const void* __restrict__ A1b, int lda1, int K1, int a1f32,
    const void* __restrict__ A2a, const void* __restrict__ A2b, int lda2, int K2, int a2f32,
    const int* __restrict__ gsrc, const int* __restrict__ gdst,
    const u16* __restrict__ Wa, const u16* __restrict__ Wb,
    const float* __restrict__ biasa, const float* __restrict__ biasb,
    int splitB, int rowD, int boundA, int nrows,
    u16* __restrict__ Cu, int ldcu, int colOff,
    u16* __restrict__ Cs, const float* __restrict__ normp,
    int act) {
  __shared__ u32 As[64 * 32];    // row-linear, granule ^= (row&7)
  __shared__ u32 Ws[128 * 32];
  const int tid = threadIdx.x;
  const bool segb = (int)blockIdx.x >= splitB;
  const int brow = segb ? rowD + ((int)blockIdx.x - splitB) * 64 : (int)blockIdx.x * 64;
  const int bound = segb ? nrows : boundA;
  const void* A1 = segb ? A1b : A1a;
  const void* A2 = segb ? A2b : A2a;
  const u16* W = segb ? Wb : Wa;
  const float* bias = segb ? biasb : biasa;
  const int K = K1 + K2;
  const int lane = tid & 63;
  const int wv = tid >> 6;
  const int wr = (wv >> 1) * 32;
  const int wc = (wv & 1) * 64;
  const int fr = lane & 15;
  const int fg = lane >> 4;

  f32x4 acc[2][4];
#pragma unroll
  for (int m = 0; m < 2; ++m)
#pragma unroll
    for (int n = 0; n < 4; ++n) acc[m][n] = (f32x4){0.f, 0.f, 0.f, 0.f};

  const int sr = tid >> 2, sk = tid & 3;
  const int swc = tid >> 1, sh = tid & 1;
  const int prow = (brow + sr < bound) ? (brow + sr) : (bound - 1);

  for (int kc = 0; kc < K; kc += 64) {
    uint4 qa0, qa1;
    {
      bool seg1 = kc < K1;
      int kk = seg1 ? kc : kc - K1;
      const void* Av = seg1 ? A1 : A2;
      int ld = seg1 ? lda1 : lda2;
      int isf = seg1 ? a1f32 : a2f32;
      int row = gsrc ? (seg1 ? gsrc[prow] : gdst[prow]) : prow;
      if (isf) {
        const float* p = (const float*)Av + (size_t)row * ld + kk + sk * 16;
        float4 f0 = ((const float4*)p)[0];
        float4 f1 = ((const float4*)p)[1];
        float4 f2 = ((const float4*)p)[2];
        float4 f3 = ((const float4*)p)[3];
        qa0 = make_uint4(pk2(f0.x, f0.y), pk2(f0.z, f0.w), pk2(f1.x, f1.y), pk2(f1.z, f1.w));
        qa1 = make_uint4(pk2(f2.x, f2.y), pk2(f2.z, f2.w), pk2(f3.x, f3.y), pk2(f3.z, f3.w));
      } else {
        const u16* p = (const u16*)Av + (size_t)row * ld + kk + sk * 16;
        qa0 = *(const uint4*)p;
        qa1 = *(const uint4*)(p + 8);
      }
    }
    const u16* wp = W + (size_t)swc * K + kc + sh * 32;
    uint4 qw0 = *(const uint4*)(wp);
    uint4 qw1 = *(const uint4*)(wp + 8);
    uint4 qw2 = *(const uint4*)(wp + 16);
    uint4 qw3 = *(const uint4*)(wp + 24);

    __syncthreads();
    *(uint4*)&As[sr * 32 + ((2 * sk)     ^ (sr & 7)) * 4] = qa0;
    *(uint4*)&As[sr * 32 + ((2 * sk + 1) ^ (sr & 7)) * 4] = qa1;
    *(uint4*)&Ws[swc * 32 + ((sh * 4 + 0) ^ (swc & 7)) * 4] = qw0;
    *(uint4*)&Ws[swc * 32 + ((sh * 4 + 1) ^ (swc & 7)) * 4] = qw1;
    *(uint4*)&Ws[swc * 32 + ((sh * 4 + 2) ^ (swc & 7)) * 4] = qw2;
    *(uint4*)&Ws[swc * 32 + ((sh * 4 + 3) ^ (swc & 7)) * 4] = qw3;
    __syncthreads();

#pragma unroll
    for (int kk2 = 0; kk2 < 2; ++kk2) {
      int gix = kk2 * 4 + fg;
      int r0 = wr + fr, r1 = wr + 16 + fr;
      bf16x8 aF0 = *(const bf16x8*)&As[r0 * 32 + (gix ^ (r0 & 7)) * 4];
      bf16x8 aF1 = *(const bf16x8*)&As[r1 * 32 + (gix ^ (r1 & 7)) * 4];
#pragma unroll
      for (int n = 0; n < 4; ++n) {
        int cr = wc + n * 16 + fr;
        bf16x8 bF = *(const bf16x8*)&Ws[cr * 32 + (gix ^ (cr & 7)) * 4];
        acc[0][n] = __builtin_amdgcn_mfma_f32_16x16x32_bf16(aF0, bF, acc[0][n], 0, 0, 0);
        acc[1][n] = __builtin_amdgcn_mfma_f32_16x16x32_bf16(aF1, bF, acc[1][n], 0, 0, 0);
      }
    }
  }

  // epilogue: D lane map col=lane&15, row=(lane>>4)*4+i  [m89]
#pragma unroll
  for (int m = 0; m < 2; ++m) {
#pragma unroll
    for (int n = 0; n < 4; ++n) {
      int ccol = wc + n * 16 + fr;
      float b = bias ? bias[ccol] : 0.f;
#pragma unroll
      for (int i = 0; i < 4; ++i) {
        int row = brow + wr + m * 16 + (lane >> 4) * 4 + i;
        if (row < bound) {
          float v = acc[m][n][i] + b;
          if (act == 1) v = (v > 0.f) ? v : (expf(v) - 1.f);
          else if (act == 2) v = fmaxf(v, 0.f);
          Cu[(size_t)row * ldcu + colOff + ccol] = f2bf(v);
          if (Cs) Cs[((size_t)row << 7) + ccol] = f2bf(v * normp[row]);
        }
      }
    }
  }
}

// ---------------- final score ----------------
__global__ void score_kernel(const u16* __restrict__ hidden, const float* __restrict__ p1w,
                             const float* __restrict__ p1b, float* __restrict__ out, int pairs) {
  int pr = blockIdx.x * 4 + (threadIdx.x >> 6);
  int lane = threadIdx.x & 63;
  if (pr >= pairs) return;
  const u16* h = hidden + (size_t)pr * 128;
  float v = bf2f(h[lane]) * p1w[lane] + bf2f(h[lane + 64]) * p1w[lane + 64];
  for (int off = 32; off > 0; off >>= 1) v += __shfl_down(v, off);
  if (lane == 0) out[pr] = 1.f / (1.f + expf(-(v + p1b[0])));
}

// ---------------- host launcher ----------------
extern "C" void kernel_launch(void* const* d_in, const int* in_sizes, int n_in,
                              void* d_out, int out_size, void* d_ws, size_t ws_size,
                              hipStream_t stream) {
  const float* d_sim   = (const float*)d_in[0];
  const float* m_sim   = (const float*)d_in[1];
  const int*   e_src   = (const int*)d_in[2];
  const int*   e_dst   = (const int*)d_in[3];
  const int*   p_src   = (const int*)d_in[4];
  const int*   p_dst   = (const int*)d_in[5];
  const float* d_fc_w  = (const float*)d_in[6];
  const float* d_fc_b  = (const float*)d_in[7];
  const float* m_fc_w  = (const float*)d_in[8];
  const float* m_fc_b  = (const float*)d_in[9];
  const float* l0_w    = (const float*)d_in[10];
  const float* l1_w    = (const float*)d_in[11];
  const float* fc_w    = (const float*)d_in[12];
  const float* d_fc1_w = (const float*)d_in[13];
  const float* d_fc1_b = (const float*)d_in[14];
  const float* m_fc1_w = (const float*)d_in[15];
  const float* m_fc1_b = (const float*)d_in[16];
  const float* p0_w    = (const float*)d_in[17];
  const float* p0_b    = (const float*)d_in[18];
  const float* p1_w    = (const float*)d_in[19];
  const float* p1_b    = (const float*)d_in[20];
  float* out = (float*)d_out;

  const int N = N_NODES, D = D_NODES, M = M_NODES, E = E_EDGES, NP = PAIRS_N;

  // ---- workspace layout (u16 units)
  u16* ws16 = (u16*)d_ws;
  u16* HCAT = ws16;                         // [N,640]
  u16* HSa  = HCAT + (size_t)N * 640;       // [N,128]
  u16* HSb  = HSa + (size_t)N * 128;        // [N,128]
  u16* FE   = HSb + (size_t)N * 128;        // [N,128] feats
  u16* HB   = FE  + (size_t)N * 128;        // [N,128] h
  u16* HID  = HB  + (size_t)N * 128;        // [NP,128] hidden
  u16* wb_dfc  = HID + (size_t)NP * 128;    // 65536
  u16* wb_mfc  = wb_dfc  + 65536;
  u16* wb_dfc1 = wb_mfc  + 65536;           // 81920
  u16* wb_mfc1 = wb_dfc1 + 81920;
  u16* wb_p0   = wb_mfc1 + 81920;           // 32768
  u16* wb_G    = wb_p0   + 32768;           // 81920 (=[128][640])
  u16* wend    = wb_G    + 81920;
  size_t off16 = (size_t)(wend - ws16);
  off16 = (off16 + 1) & ~(size_t)1;
  float* Tmp   = (float*)(ws16 + off16);    // 9*128*128 f32
  float* normp = Tmp + 9 * 16384;
  int* degs    = (int*)(normp + N);
  int* csr_off = degs + N;                  // N+1
  int* cursor  = csr_off + N + 1;           // N
  int* csr_src = cursor + N;                // E
  int* bsums   = csr_src + E;               // <=256

  const int nb = (N + 255) / 256;
  const int eb = (E + 255) / 256;

  // ---- weights -> bf16 ; weight combine (independent of graph/CSR)
  wconv_kernel<<<320, 256, 0, stream>>>(d_fc_w, m_fc_w, d_fc1_w, m_fc1_w, p0_w,
                                        wb_dfc, wb_mfc, wb_dfc1, wb_mfc1, wb_p0);
  wcomb1_kernel<<<dim3(9, 128), 128, 0, stream>>>(l1_w, l0_w, Tmp);
  wcomb2_kernel<<<dim3(5, 128), 128, 0, stream>>>(fc_w, Tmp, wb_G);

  // ---- degrees, norm, CSR-by-dst
  hipMemsetAsync(degs, 0, (size_t)N * 4, stream);
  deg_count_kernel<<<eb, 256, 0, stream>>>(e_dst, degs, E);
  norm_reduce_kernel<<<nb, 256, 0, stream>>>(degs, normp, N, bsums);
  scan_small_kernel<<<1, 256, 0, stream>>>(bsums, nb);
  scan_final_kernel<<<nb, 256, 0, stream>>>(degs, bsums, csr_off, cursor, N, E);
  fill_csr_kernel<<<eb, 256, 0, stream>>>(e_src, e_dst, cursor, csr_src, E);

  const int GDseg = (D + 63) / 64;           // 313
  const int GMseg = (M + 63) / 64;           // 469 (rows D..N, 64-chunks from D)
  const int GSEG = GDseg + GMseg;
  const int GN = (N + 63) / 64, GP = (NP + 63) / 64;

  // ---- proj (segmented d/m, fp32 A): H0 -> HCAT[:,0:128], H0s -> HSa
  mfma_gemm_kernel<<<GSEG, 256, 0, stream>>>(
      d_sim, m_sim, 512, 512, 1, nullptr, nullptr, 0, 0, 0, nullptr, nullptr,
      wb_dfc, wb_mfc, d_fc_b, m_fc_b, GDseg, D, D, N,
      HCAT, 640, 0, HSa, normp, 0);

  // ---- 4 sequential 128-wide props: H1..H4 -> HCAT col-blocks, scaled ping-pong
  prop128_kernel<<<N, 128, 0, stream>>>(HSa, HCAT, 640, 128, HSb, csr_off, csr_src, normp);
  prop128_kernel<<<N, 128, 0, stream>>>(HSb, HCAT, 640, 256, HSa, csr_off, csr_src, normp);
  prop128_kernel<<<N, 128, 0, stream>>>(HSa, HCAT, 640, 384, HSb, csr_off, csr_src, normp);
  prop128_kernel<<<N, 128, 0, stream>>>(HSb, HCAT, 640, 512, nullptr, csr_off, csr_src, normp);

  // ---- collapsed mixhop+fc: feats = HCAT [N,640] @ G^T -> FE
  mfma_gemm_kernel<<<GN, 256, 0, stream>>>(
      HCAT, HCAT, 640, 640, 0, nullptr, nullptr, 0, 0, 0, nullptr, nullptr,
      wb_G, wb_G, nullptr, nullptr, GN, 0, N, N,
      FE, 128, 0, nullptr, normp, 0);

  // ---- fc1 (+ELU, segmented d/m, A2 = fp32 sims): h -> HB
  mfma_gemm_kernel<<<GSEG, 256, 0, stream>>>(
      FE, FE, 128, 128, 0, d_sim, m_sim, 512, 512, 1, nullptr, nullptr,
      wb_dfc1, wb_mfc1, d_fc1_b, m_fc1_b, GDseg, D, D, N,
      HB, 128, 0, nullptr, normp, 1);

  // ---- predictor p0 (gathered concat) + ReLU: hidden -> HID
  mfma_gemm_kernel<<<GP, 256, 0, stream>>>(
      HB, HB, 128, 128, 0, HB, HB, 128, 128, 0, p_src, p_dst,
      wb_p0, wb_p0, p0_b, p0_b, GP, 0, NP, NP,
      HID, 128, 0, nullptr, normp, 2);

  // ---- final dot + sigmoid
  score_kernel<<<(NP + 3) / 4, 256, 0, stream>>>(HID, p1_w, p1_b, out, NP);

  (void)in_sizes; (void)n_in; (void)out_size; (void)ws_size;
}

// Round 5
// 379.085 us; speedup vs baseline: 4.1888x; 1.1449x over previous
//
#include <hip/hip_runtime.h>
#include <cstddef>
#include <cstdint>

#define N_NODES 50000
#define D_NODES 20000
#define M_NODES 30000
#define E_EDGES 800000
#define PAIRS_N 100000

typedef unsigned short u16;
typedef unsigned int u32;
typedef short bf16x8 __attribute__((ext_vector_type(8)));
typedef float f32x4 __attribute__((ext_vector_type(4)));

__device__ __forceinline__ float bf2f(u16 u) {
  u32 v = ((u32)u) << 16;
  return __builtin_bit_cast(float, v);
}
__device__ __forceinline__ u16 f2bf(float f) {
  u32 u = __builtin_bit_cast(u32, f);
  u32 r = (u + 0x7fffu + ((u >> 16) & 1u)) >> 16;  // RNE
  return (u16)r;
}
__device__ __forceinline__ u32 pk2(float x, float y) {
  return (u32)f2bf(x) | ((u32)f2bf(y) << 16);
}

// ---------------- weight conversion (5 mats -> bf16, one launch) ----------------
__global__ void wconv_kernel(const float* s0, const float* s1, const float* s2,
                             const float* s3, const float* s4,
                             u16* d0, u16* d1, u16* d2, u16* d3, u16* d4) {
  int i = blockIdx.x * 256 + threadIdx.x;  // quad index
  const float* s; u16* d; int l;
  if      (i < 16384) { s = s0; d = d0; l = i; }
  else if (i < 32768) { s = s1; d = d1; l = i - 16384; }
  else if (i < 53248) { s = s2; d = d2; l = i - 32768; }
  else if (i < 73728) { s = s3; d = d3; l = i - 53248; }
  else if (i < 81920) { s = s4; d = d4; l = i - 73728; }
  else return;
  float4 v = *(const float4*)(s + (size_t)l * 4);
  ushort4 o;
  o.x = f2bf(v.x); o.y = f2bf(v.y); o.z = f2bf(v.z); o.w = f2bf(v.w);
  *(ushort4*)(d + (size_t)l * 4) = o;
}

// ---------------- weight combine: G_k = sum_{p+j=k} fc_p * W'_pj * W_j ----------
__global__ void wcomb1_kernel(const float* __restrict__ l1w, const float* __restrict__ l0w,
                              float* __restrict__ Tmp) {
  int pj = blockIdx.x;          // 0..8
  int p = pj / 3, j = pj % 3;
  int o = blockIdx.y;           // 0..127
  int i = threadIdx.x;          // 0..127
  const float* wp = l1w + (size_t)p * 49152 + (size_t)o * 384 + 128 * j;
  const float* wj = l0w + (size_t)j * 16384 + i;
  float acc = 0.f;
#pragma unroll 4
  for (int t = 0; t < 128; ++t) acc += wp[t] * wj[(size_t)t * 128];
  Tmp[(size_t)pj * 16384 + (size_t)o * 128 + i] = acc;
}
__global__ void wcomb2_kernel(const float* __restrict__ fcw, const float* __restrict__ Tmp,
                              u16* __restrict__ G) {
  int k = blockIdx.x;           // 0..4
  int of = blockIdx.y;          // 0..127
  int i = threadIdx.x;          // 0..127
  float acc = 0.f;
  int plo = (k > 2) ? (k - 2) : 0;
  int phi = (k < 2) ? k : 2;
  for (int p = plo; p <= phi; ++p) {
    int j = k - p;
    const float* fp = fcw + (size_t)of * 384 + 128 * p;
    const float* tp = Tmp + (size_t)(p * 3 + j) * 16384 + i;
#pragma unroll 4
    for (int t = 0; t < 128; ++t) acc += fp[t] * tp[(size_t)t * 128];
  }
  G[(size_t)of * 640 + 128 * k + i] = f2bf(acc);
}

// ---------------- CSR build ----------------
__global__ void deg_count_kernel(const int* __restrict__ dst, int* __restrict__ degs, int e) {
  int i = blockIdx.x * 256 + threadIdx.x;
  if (i < e) atomicAdd(&degs[dst[i]], 1);
}
__global__ void norm_reduce_kernel(const int* __restrict__ degs, float* __restrict__ norm,
                                   int n, int* __restrict__ bsums) {
  __shared__ int s[256];
  int t = threadIdx.x;
  int i = blockIdx.x * 256 + t;
  int d = (i < n) ? degs[i] : 0;
  if (i < n) norm[i] = rsqrtf(fmaxf((float)d, 1.0f));
  s[t] = d;
  __syncthreads();
  for (int st = 128; st > 0; st >>= 1) {
    if (t < st) s[t] += s[t + st];
    __syncthreads();
  }
  if (t == 0) bsums[blockIdx.x] = s[0];
}
__global__ void scan_small_kernel(int* b, int nb) {
  __shared__ int s[256];
  int t = threadIdx.x;
  int orig = (t < nb) ? b[t] : 0;
  s[t] = orig;
  __syncthreads();
  for (int st = 1; st < 256; st <<= 1) {
    int v = (t >= st) ? s[t - st] : 0;
    __syncthreads();
    s[t] += v;
    __syncthreads();
  }
  if (t < nb) b[t] = s[t] - orig;
}
__global__ void scan_final_kernel(const int* __restrict__ degs, const int* __restrict__ boff,
                                  int* __restrict__ out, int* __restrict__ cursor,
                                  int n, int total) {
  __shared__ int s[256];
  int t = threadIdx.x;
  int i = blockIdx.x * 256 + t;
  int orig = (i < n) ? degs[i] : 0;
  s[t] = orig;
  __syncthreads();
  for (int st = 1; st < 256; st <<= 1) {
    int v = (t >= st) ? s[t - st] : 0;
    __syncthreads();
    s[t] += v;
    __syncthreads();
  }
  if (i < n) {
    int v = boff[blockIdx.x] + s[t] - orig;
    out[i] = v;
    cursor[i] = v;
  }
  if (i == 0) out[n] = total;
}
__global__ void fill_csr_kernel(const int* __restrict__ esrc, const int* __restrict__ edst,
                                int* __restrict__ cursor, int* __restrict__ csr_src, int e) {
  int i = blockIdx.x * 256 + threadIdx.x;
  if (i < e) {
    int p = atomicAdd(&cursor[edst[i]], 1);
    csr_src[p] = esrc[i];
  }
}

// ---------------- wave-per-node 128-wide propagation on pre-scaled input --------
// 64 lanes x 2 channels; per edge one 4B load/lane (256B line). src idx broadcast
// via readlane; 8-deep unroll for outstanding loads. No LDS, no barriers.
__global__ void prop_kernel(const u16* __restrict__ in,
                            u16* __restrict__ outu, int ldu, int cOff,
                            u16* __restrict__ outs,
                            const int* __restrict__ off, const int* __restrict__ srcs,
                            const float* __restrict__ norm, int nnodes) {
  const int node = blockIdx.x * 4 + (threadIdx.x >> 6);
  if (node >= nnodes) return;
  const int lane = threadIdx.x & 63;
  const int e0 = off[node], e1 = off[node + 1];
  float a0 = 0.f, a1 = 0.f;
  const u16* basec = in + (lane << 1);
  for (int base = e0; base < e1; base += 64) {
    int nE = e1 - base; if (nE > 64) nE = 64;
    int myE = srcs[base + ((lane < nE) ? lane : (nE - 1))];
    int i = 0;
    for (; i + 8 <= nE; i += 8) {
      int s0 = __builtin_amdgcn_readlane(myE, i + 0);
      int s1 = __builtin_amdgcn_readlane(myE, i + 1);
      int s2 = __builtin_amdgcn_readlane(myE, i + 2);
      int s3 = __builtin_amdgcn_readlane(myE, i + 3);
      int s4 = __builtin_amdgcn_readlane(myE, i + 4);
      int s5 = __builtin_amdgcn_readlane(myE, i + 5);
      int s6 = __builtin_amdgcn_readlane(myE, i + 6);
      int s7 = __builtin_amdgcn_readlane(myE, i + 7);
      u32 v0 = *(const u32*)(basec + ((size_t)s0 << 7));
      u32 v1 = *(const u32*)(basec + ((size_t)s1 << 7));
      u32 v2 = *(const u32*)(basec + ((size_t)s2 << 7));
      u32 v3 = *(const u32*)(basec + ((size_t)s3 << 7));
      u32 v4 = *(const u32*)(basec + ((size_t)s4 << 7));
      u32 v5 = *(const u32*)(basec + ((size_t)s5 << 7));
      u32 v6 = *(const u32*)(basec + ((size_t)s6 << 7));
      u32 v7 = *(const u32*)(basec + ((size_t)s7 << 7));
      a0 += bf2f((u16)v0); a1 += bf2f((u16)(v0 >> 16));
      a0 += bf2f((u16)v1); a1 += bf2f((u16)(v1 >> 16));
      a0 += bf2f((u16)v2); a1 += bf2f((u16)(v2 >> 16));
      a0 += bf2f((u16)v3); a1 += bf2f((u16)(v3 >> 16));
      a0 += bf2f((u16)v4); a1 += bf2f((u16)(v4 >> 16));
      a0 += bf2f((u16)v5); a1 += bf2f((u16)(v5 >> 16));
      a0 += bf2f((u16)v6); a1 += bf2f((u16)(v6 >> 16));
      a0 += bf2f((u16)v7); a1 += bf2f((u16)(v7 >> 16));
    }
    for (; i < nE; ++i) {
      int s = __builtin_amdgcn_readlane(myE, i);
      u32 v = *(const u32*)(basec + ((size_t)s << 7));
      a0 += bf2f((u16)v); a1 += bf2f((u16)(v >> 16));
    }
  }
  float nd = norm[node];
  *(u32*)(outu + (size_t)node * ldu + cOff + (lane << 1)) = pk2(a0 * nd, a1 * nd);
  if (outs) {
    float nd2 = nd * nd;
    *(u32*)(outs + ((size_t)node << 7) + (lane << 1)) = pk2(a0 * nd2, a1 * nd2);
  }
}

// ---------------- bf16 MFMA GEMM (BM=32, BK=64, XOR-swizzled LDS) ----------------
// Segmented (blocks >= splitB use b-pointers, rows from rowD). fp32 A converted in
// staging. Gather via gsrc/gdst. act: 0 none, 1 ELU, 2 ReLU, 3 fused p0+score.
__global__ __launch_bounds__(256) void mfma_gemm_kernel(
    const void* __restrict__ A1a, const void* __restrict__ A1b, int lda1, int K1, int a1f32,
    const void* __restrict__ A2a, const void* __restrict__ A2b, int lda2, int K2, int a2f32,
    const int* __restrict__ gsrc, const int* __restrict__ gdst,
    const u16* __restrict__ Wa, const u16* __restrict__ Wb,
    const float* __restrict__ biasa, const float* __restrict__ biasb,
    int splitB, int rowD, int boundA, int nrows,
    u16* __restrict__ Cu, int ldcu, int colOff,
    u16* __restrict__ Cs, const float* __restrict__ normp,
    const float* __restrict__ p1w, const float* __restrict__ p1b, float* __restrict__ outf,
    int act) {
  __shared__ u32 As[32 * 32];    // 4 KB
  __shared__ u32 Ws[128 * 32];   // 16 KB
  const int tid = threadIdx.x;
  const bool segb = (int)blockIdx.x >= splitB;
  const int brow = segb ? rowD + ((int)blockIdx.x - splitB) * 32 : (int)blockIdx.x * 32;
  const int bound = segb ? nrows : boundA;
  const void* A1 = segb ? A1b : A1a;
  const void* A2 = segb ? A2b : A2a;
  const u16* W = segb ? Wb : Wa;
  const float* bias = segb ? biasb : biasa;
  const int K = K1 + K2;
  const int lane = tid & 63;
  const int wv = tid >> 6;
  const int fr = lane & 15;
  const int fg = lane >> 4;

  f32x4 acc[2][2];
#pragma unroll
  for (int m = 0; m < 2; ++m)
#pragma unroll
    for (int n = 0; n < 2; ++n) acc[m][n] = (f32x4){0.f, 0.f, 0.f, 0.f};

  const int sr = tid >> 3, sk = tid & 7;     // A: row, granule (8 bf16)
  const int swc = tid >> 1, sh = tid & 1;    // W: row, 32-elem half
  const int prow = (brow + sr < bound) ? (brow + sr) : (bound - 1);

  for (int kc = 0; kc < K; kc += 64) {
    // ---- A: 8 k-elems per thread
    uint4 qa;
    {
      bool seg1 = kc < K1;
      int kk = (seg1 ? kc : kc - K1) + sk * 8;
      const void* Av = seg1 ? A1 : A2;
      int ld = seg1 ? lda1 : lda2;
      int isf = seg1 ? a1f32 : a2f32;
      int row = gsrc ? (seg1 ? gsrc[prow] : gdst[prow]) : prow;
      if (isf) {
        const float* p = (const float*)Av + (size_t)row * ld + kk;
        float4 f0 = ((const float4*)p)[0];
        float4 f1 = ((const float4*)p)[1];
        qa = make_uint4(pk2(f0.x, f0.y), pk2(f0.z, f0.w), pk2(f1.x, f1.y), pk2(f1.z, f1.w));
      } else {
        qa = *(const uint4*)((const u16*)Av + (size_t)row * ld + kk);
      }
    }
    // ---- W: 32 k-elems per thread
    const u16* wp = W + (size_t)swc * K + kc + sh * 32;
    uint4 qw0 = *(const uint4*)(wp);
    uint4 qw1 = *(const uint4*)(wp + 8);
    uint4 qw2 = *(const uint4*)(wp + 16);
    uint4 qw3 = *(const uint4*)(wp + 24);

    __syncthreads();
    *(uint4*)&As[sr * 32 + (sk ^ (sr & 7)) * 4] = qa;
    *(uint4*)&Ws[swc * 32 + ((sh * 4 + 0) ^ (swc & 7)) * 4] = qw0;
    *(uint4*)&Ws[swc * 32 + ((sh * 4 + 1) ^ (swc & 7)) * 4] = qw1;
    *(uint4*)&Ws[swc * 32 + ((sh * 4 + 2) ^ (swc & 7)) * 4] = qw2;
    *(uint4*)&Ws[swc * 32 + ((sh * 4 + 3) ^ (swc & 7)) * 4] = qw3;
    __syncthreads();

#pragma unroll
    for (int kk2 = 0; kk2 < 2; ++kk2) {
      int gix = kk2 * 4 + fg;
      int r0 = fr, r1 = 16 + fr;
      bf16x8 aF0 = *(const bf16x8*)&As[r0 * 32 + (gix ^ (r0 & 7)) * 4];
      bf16x8 aF1 = *(const bf16x8*)&As[r1 * 32 + (gix ^ (r1 & 7)) * 4];
#pragma unroll
      for (int n = 0; n < 2; ++n) {
        int cr = wv * 32 + n * 16 + fr;
        bf16x8 bF = *(const bf16x8*)&Ws[cr * 32 + (gix ^ (cr & 7)) * 4];
        acc[0][n] = __builtin_amdgcn_mfma_f32_16x16x32_bf16(aF0, bF, acc[0][n], 0, 0, 0);
        acc[1][n] = __builtin_amdgcn_mfma_f32_16x16x32_bf16(aF1, bF, acc[1][n], 0, 0, 0);
      }
    }
  }

  if (act == 3) {
    // fused p0 bias+ReLU, dot with p1w, sigmoid -> outf[row]
    float part[2][4];
#pragma unroll
    for (int m = 0; m < 2; ++m)
#pragma unroll
      for (int i = 0; i < 4; ++i) part[m][i] = 0.f;
#pragma unroll
    for (int n = 0; n < 2; ++n) {
      int ccol = wv * 32 + n * 16 + fr;
      float b = bias[ccol];
      float pw = p1w[ccol];
#pragma unroll
      for (int m = 0; m < 2; ++m)
#pragma unroll
        for (int i = 0; i < 4; ++i) {
          float v = acc[m][n][i] + b;
          v = fmaxf(v, 0.f);
          part[m][i] += v * pw;
        }
    }
#pragma unroll
    for (int mask = 1; mask <= 8; mask <<= 1)
#pragma unroll
      for (int m = 0; m < 2; ++m)
#pragma unroll
        for (int i = 0; i < 4; ++i) part[m][i] += __shfl_xor(part[m][i], mask);
    __syncthreads();                 // all LDS frag reads done before reuse
    float* sred = (float*)As;        // [4][32]
    if (fr == 0) {
#pragma unroll
      for (int m = 0; m < 2; ++m)
#pragma unroll
        for (int i = 0; i < 4; ++i) sred[wv * 32 + m * 16 + fg * 4 + i] = part[m][i];
    }
    __syncthreads();
    if (tid < 32) {
      int row = brow + tid;
      if (row < bound) {
        float s = sred[tid] + sred[32 + tid] + sred[64 + tid] + sred[96 + tid] + p1b[0];
        outf[row] = 1.f / (1.f + expf(-s));
      }
    }
    return;
  }

  // ---- epilogue: D lane map col=lane&15, row=(lane>>4)*4+i  [m89]
#pragma unroll
  for (int m = 0; m < 2; ++m) {
#pragma unroll
    for (int n = 0; n < 2; ++n) {
      int ccol = wv * 32 + n * 16 + fr;
      float b = bias ? bias[ccol] : 0.f;
#pragma unroll
      for (int i = 0; i < 4; ++i) {
        int row = brow + m * 16 + fg * 4 + i;
        if (row < bound) {
          float v = acc[m][n][i] + b;
          if (act == 1) v = (v > 0.f) ? v : (expf(v) - 1.f);
          else if (act == 2) v = fmaxf(v, 0.f);
          Cu[(size_t)row * ldcu + colOff + ccol] = f2bf(v);
          if (Cs) Cs[((size_t)row << 7) + ccol] = f2bf(v * normp[row]);
        }
      }
    }
  }
}

// ---------------- host launcher ----------------
extern "C" void kernel_launch(void* const* d_in, const int* in_sizes, int n_in,
                              void* d_out, int out_size, void* d_ws, size_t ws_size,
                              hipStream_t stream) {
  const float* d_sim   = (const float*)d_in[0];
  const float* m_sim   = (const float*)d_in[1];
  const int*   e_src   = (const int*)d_in[2];
  const int*   e_dst   = (const int*)d_in[3];
  const int*   p_src   = (const int*)d_in[4];
  const int*   p_dst   = (const int*)d_in[5];
  const float* d_fc_w  = (const float*)d_in[6];
  const float* d_fc_b  = (const float*)d_in[7];
  const float* m_fc_w  = (const float*)d_in[8];
  const float* m_fc_b  = (const float*)d_in[9];
  const float* l0_w    = (const float*)d_in[10];
  const float* l1_w    = (const float*)d_in[11];
  const float* fc_w    = (const float*)d_in[12];
  const float* d_fc1_w = (const float*)d_in[13];
  const float* d_fc1_b = (const float*)d_in[14];
  const float* m_fc1_w = (const float*)d_in[15];
  const float* m_fc1_b = (const float*)d_in[16];
  const float* p0_w    = (const float*)d_in[17];
  const float* p0_b    = (const float*)d_in[18];
  const float* p1_w    = (const float*)d_in[19];
  const float* p1_b    = (const float*)d_in[20];
  float* out = (float*)d_out;

  const int N = N_NODES, D = D_NODES, M = M_NODES, E = E_EDGES, NP = PAIRS_N;

  // ---- workspace layout (u16 units)
  u16* ws16 = (u16*)d_ws;
  u16* HCAT = ws16;                         // [N,640]
  u16* HSa  = HCAT + (size_t)N * 640;       // [N,128]
  u16* HSb  = HSa + (size_t)N * 128;        // [N,128]
  u16* FE   = HSb + (size_t)N * 128;        // [N,128] feats
  u16* HB   = FE  + (size_t)N * 128;        // [N,128] h
  u16* wb_dfc  = HB + (size_t)N * 128;      // 65536
  u16* wb_mfc  = wb_dfc  + 65536;
  u16* wb_dfc1 = wb_mfc  + 65536;           // 81920
  u16* wb_mfc1 = wb_dfc1 + 81920;
  u16* wb_p0   = wb_mfc1 + 81920;           // 32768
  u16* wb_G    = wb_p0   + 32768;           // 81920 ([128][640])
  u16* wend    = wb_G    + 81920;
  size_t off16 = (size_t)(wend - ws16);
  off16 = (off16 + 1) & ~(size_t)1;
  float* Tmp   = (float*)(ws16 + off16);    // 9*128*128 f32
  float* normp = Tmp + 9 * 16384;
  int* degs    = (int*)(normp + N);
  int* csr_off = degs + N;                  // N+1
  int* cursor  = csr_off + N + 1;           // N
  int* csr_src = cursor + N;                // E
  int* bsums   = csr_src + E;               // <=256

  const int nb = (N + 255) / 256;
  const int eb = (E + 255) / 256;

  // ---- weights -> bf16 ; weight combine (independent of graph/CSR)
  wconv_kernel<<<320, 256, 0, stream>>>(d_fc_w, m_fc_w, d_fc1_w, m_fc1_w, p0_w,
                                        wb_dfc, wb_mfc, wb_dfc1, wb_mfc1, wb_p0);
  wcomb1_kernel<<<dim3(9, 128), 128, 0, stream>>>(l1_w, l0_w, Tmp);
  wcomb2_kernel<<<dim3(5, 128), 128, 0, stream>>>(fc_w, Tmp, wb_G);

  // ---- degrees, norm, CSR-by-dst
  hipMemsetAsync(degs, 0, (size_t)N * 4, stream);
  deg_count_kernel<<<eb, 256, 0, stream>>>(e_dst, degs, E);
  norm_reduce_kernel<<<nb, 256, 0, stream>>>(degs, normp, N, bsums);
  scan_small_kernel<<<1, 256, 0, stream>>>(bsums, nb);
  scan_final_kernel<<<nb, 256, 0, stream>>>(degs, bsums, csr_off, cursor, N, E);
  fill_csr_kernel<<<eb, 256, 0, stream>>>(e_src, e_dst, cursor, csr_src, E);

  const int GDseg = D / 32;                  // 625
  const int GMseg = (M + 31) / 32;           // 938
  const int GSEG = GDseg + GMseg;
  const int GN = (N + 31) / 32;              // 1563
  const int GP = (NP + 31) / 32;             // 3125
  const int GPROP = (N + 3) / 4;             // 12500

  // ---- proj (segmented d/m, fp32 A): H0 -> HCAT[:,0:128], scaled H0 -> HSa
  mfma_gemm_kernel<<<GSEG, 256, 0, stream>>>(
      d_sim, m_sim, 512, 512, 1, nullptr, nullptr, 0, 0, 0, nullptr, nullptr,
      wb_dfc, wb_mfc, d_fc_b, m_fc_b, GDseg, D, D, N,
      HCAT, 640, 0, HSa, normp, nullptr, nullptr, nullptr, 0);

  // ---- 4 sequential 128-wide props: H1..H4 -> HCAT col-blocks, scaled ping-pong
  prop_kernel<<<GPROP, 256, 0, stream>>>(HSa, HCAT, 640, 128, HSb, csr_off, csr_src, normp, N);
  prop_kernel<<<GPROP, 256, 0, stream>>>(HSb, HCAT, 640, 256, HSa, csr_off, csr_src, normp, N);
  prop_kernel<<<GPROP, 256, 0, stream>>>(HSa, HCAT, 640, 384, HSb, csr_off, csr_src, normp, N);
  prop_kernel<<<GPROP, 256, 0, stream>>>(HSb, HCAT, 640, 512, nullptr, csr_off, csr_src, normp, N);

  // ---- collapsed mixhop+fc: feats = HCAT [N,640] @ G^T -> FE
  mfma_gemm_kernel<<<GN, 256, 0, stream>>>(
      HCAT, HCAT, 640, 640, 0, nullptr, nullptr, 0, 0, 0, nullptr, nullptr,
      wb_G, wb_G, nullptr, nullptr, GN, 0, N, N,
      FE, 128, 0, nullptr, normp, nullptr, nullptr, nullptr, 0);

  // ---- fc1 (+ELU, segmented d/m, A2 = fp32 sims): h -> HB
  mfma_gemm_kernel<<<GSEG, 256, 0, stream>>>(
      FE, FE, 128, 128, 0, d_sim, m_sim, 512, 512, 1, nullptr, nullptr,
      wb_dfc1, wb_mfc1, d_fc1_b, m_fc1_b, GDseg, D, D, N,
      HB, 128, 0, nullptr, normp, nullptr, nullptr, nullptr, 1);

  // ---- predictor p0 (gathered concat) + ReLU + dot(p1) + sigmoid -> out
  mfma_gemm_kernel<<<GP, 256, 0, stream>>>(
      HB, HB, 128, 128, 0, HB, HB, 128, 128, 0, p_src, p_dst,
      wb_p0, wb_p0, p0_b, p0_b, GP, 0, NP, NP,
      nullptr, 128, 0, nullptr, normp, p1_w, p1_b, out, 3);

  (void)in_sizes; (void)n_in; (void)out_size; (void)ws_size;
}